// Round 9
// baseline (231.189 us; speedup 1.0000x reference)
//
#include <hip/hip_runtime.h>
#include <hip/hip_bf16.h>

typedef unsigned short u16;
typedef __attribute__((ext_vector_type(4))) float f32x4;
typedef __attribute__((ext_vector_type(8))) short short8;

#define NB   8
#define CIN  256
#define EDIM 256
#define M3   768
#define HWN  4096
#define LND  64
#define NS2  72    // NS LDS row stride (bf16 elems): 144B, 16B aligned

__device__ __forceinline__ float bf2f(u16 u){ return __uint_as_float(((unsigned)u)<<16); }
__device__ __forceinline__ u16 f2bf(float f){ __hip_bfloat16 h = __float2bfloat16(f); return *reinterpret_cast<u16*>(&h); }
__device__ __forceinline__ void bf2x2(unsigned u, float &lo, float &hi){
  lo = __uint_as_float(u<<16);
  hi = __uint_as_float(u & 0xffff0000u);
}

typedef __attribute__((address_space(1))) unsigned as1_uint;
typedef __attribute__((address_space(3))) unsigned as3_uint;
// async global->LDS, 16B per lane; dest must be wave-uniform base + lane*16
__device__ __forceinline__ void gl16(const void* g, void* l){
  __builtin_amdgcn_global_load_lds((const as1_uint*)g, (as3_uint*)l, 16, 0, 0);
}

// ---------------- prep: Xt[n][p][c] (bf16) = transpose of X[n][c][p] (fp32) ----------------
// blocks >= 2048: convert w_qkv / w_out to bf16 (once, instead of per GEMM block)
__global__ __launch_bounds__(256) void k_prep(const float* __restrict__ x, u16* __restrict__ Xt,
                                              const float* __restrict__ wq, const float* __restrict__ wo,
                                              u16* __restrict__ Wqb, u16* __restrict__ Wob){
  const int bi = blockIdx.x;
  const int tid = threadIdx.x;
  if(bi >= 2048){
    int ti = (bi-2048)*256 + tid;          // 0..2047
    const float* src; u16* dst;
    if(ti < 1536){ src = wq + (size_t)ti*128;        dst = Wqb + (size_t)ti*128; }
    else         { src = wo + (size_t)(ti-1536)*128; dst = Wob + (size_t)(ti-1536)*128; }
    #pragma unroll
    for(int t=0;t<128;t+=8){
      float4 v0 = *(const float4*)(src+t);
      float4 v1 = *(const float4*)(src+t+4);
      ushort4 o0, o1;
      o0.x=f2bf(v0.x); o0.y=f2bf(v0.y); o0.z=f2bf(v0.z); o0.w=f2bf(v0.w);
      o1.x=f2bf(v1.x); o1.y=f2bf(v1.y); o1.z=f2bf(v1.z); o1.w=f2bf(v1.w);
      *(ushort4*)(dst+t)   = o0;
      *(ushort4*)(dst+t+4) = o1;
    }
    return;
  }
  __shared__ float Ts[64*65];
  const int n = bi>>8, rem = bi&255, ct = rem>>6, pt = rem&63;
  const int c0 = ct*64, p0 = pt*64;
  {
    int cc = tid>>2, pj = (tid&3)*16;
    const float* xp = x + (size_t)n*CIN*HWN + (size_t)(c0+cc)*HWN + p0 + pj;
    #pragma unroll
    for(int j=0;j<16;j++) Ts[cc*65 + pj + j] = xp[j];
  }
  __syncthreads();
  {
    int pp = tid>>2, ej = (tid&3)*16;
    u16* op = Xt + ((size_t)n*HWN + p0 + pp)*CIN + c0 + ej;
    ushort4 o[4];
    #pragma unroll
    for(int j=0;j<16;j++) ((u16*)o)[j] = f2bf(Ts[(ej+j)*65 + pp]);
    *(ushort4*)(op+0)  = o[0];
    *(ushort4*)(op+4)  = o[1];
    *(ushort4*)(op+8)  = o[2];
    *(ushort4*)(op+12) = o[3];
  }
}

// ---------------- QKV GEMM 128x128xK256 bf16 MFMA, global_load_lds + XOR swizzle ------------
__global__ __launch_bounds__(256) void k_qkv(const u16* __restrict__ Wb, const u16* __restrict__ Xt,
                                             const float* __restrict__ bias, u16* __restrict__ Y){
  __shared__ __align__(16) u16 As[128*64];
  __shared__ __align__(16) u16 Bs[128*64];
  const int bi = blockIdx.x;
  const int n = bi&7, rem = bi>>3;
  const int ch0 = (rem%6)*128, p0 = (rem/6)*128;
  const int tid = threadIdx.x, lane = tid&63;
  const int c = tid&15, qq = (tid>>4)&3, w4 = tid>>6;
  const int wr0 = (w4&1)*64, wc0 = (w4>>1)*64;
  const u16* xb = Xt + ((size_t)n*HWN + p0)*CIN;
  const u16* wb = Wb + (size_t)ch0*CIN;
  f32x4 acc[4][4];
  #pragma unroll
  for(int mt=0;mt<4;mt++)
    #pragma unroll
    for(int nt=0;nt<4;nt++){ acc[mt][nt][0]=0.f; acc[mt][nt][1]=0.f; acc[mt][nt][2]=0.f; acc[mt][nt][3]=0.f; }
  const int srow  = w4*8 + (lane>>3);
  const int dslot = lane&7;
  const int sgo   = (dslot ^ (lane>>3))*8;       // swizzled source u16 offset within row-chunk
  const int rdswz = (c&7);                        // read-side row&7
  for(int ph=0; ph<4; ph++){
    #pragma unroll
    for(int j=0;j<4;j++){
      int r = j*32 + srow;
      gl16(wb + (size_t)r*CIN + ph*64 + sgo, &As[r*64 + dslot*8]);
    }
    #pragma unroll
    for(int j=0;j<4;j++){
      int r = j*32 + srow;
      gl16(xb + (size_t)r*CIN + ph*64 + sgo, &Bs[r*64 + dslot*8]);
    }
    __syncthreads();
    #pragma unroll
    for(int kt=0;kt<2;kt++){
      short8 af[4], bff[4];
      const int rslot = ((kt*4+qq)^rdswz)*8;
      #pragma unroll
      for(int mt=0;mt<4;mt++) af[mt]  = *(const short8*)&As[(wr0+mt*16+c)*64 + rslot];
      #pragma unroll
      for(int nt=0;nt<4;nt++) bff[nt] = *(const short8*)&Bs[(wc0+nt*16+c)*64 + rslot];
      #pragma unroll
      for(int mt=0;mt<4;mt++)
        #pragma unroll
        for(int nt=0;nt<4;nt++)
          acc[mt][nt] = __builtin_amdgcn_mfma_f32_16x16x32_bf16(af[mt], bff[nt], acc[mt][nt], 0, 0, 0);
    }
    __syncthreads();
  }
  u16* Yb = Y + (size_t)n*M3*HWN;
  #pragma unroll
  for(int mt=0;mt<4;mt++){
    int chb = ch0 + wr0 + mt*16 + 4*qq;
    float b0 = bias[chb], b1 = bias[chb+1], b2 = bias[chb+2], b3 = bias[chb+3];
    #pragma unroll
    for(int nt=0;nt<4;nt++){
      int p = p0 + wc0 + nt*16 + c;
      u16* yp = Yb + (size_t)chb*HWN + p;
      yp[0]             = f2bf(acc[mt][nt][0]+b0);
      yp[HWN]           = f2bf(acc[mt][nt][1]+b1);
      yp[2*(size_t)HWN] = f2bf(acc[mt][nt][2]+b2);
      yp[3*(size_t)HWN] = f2bf(acc[mt][nt][3]+b3);
    }
  }
}

// ---------------- landmarks ----------------
__global__ void k_land(const u16* __restrict__ Y, float* __restrict__ qland, float* __restrict__ kland){
  const int l = blockIdx.x, n = blockIdx.y, e = threadIdx.x;
  const u16* base = Y + (size_t)n*M3*HWN;
  float qs=0.f, ks=0.f;
  #pragma unroll 8
  for(int m=0;m<64;m++){
    size_t off = (size_t)(l*64+m)*M3;
    qs += bf2f(base[off+e]);
    ks += bf2f(base[off+256+e]);
  }
  qland[((size_t)n*LND+l)*EDIM+e] = qs*(1.f/4096.f);
  kland[((size_t)n*LND+l)*EDIM+e] = ks*(1.f/4096.f);
}

// ---------------- single-wave 64x64 matmul: out[mt][tc] += A @ B^T (16x16x32 MFMA tiles) ----
// A rows from L (stride sL), B^T rows from Rt (stride sR). One 64-lane wave, no barriers.
__device__ __forceinline__ void ns_mm_w(const u16* L, int sL, const u16* Rt, int sR,
                                        int q, int c, f32x4 out[4][4]){
  short8 bfr[4][2];
  #pragma unroll
  for(int tc=0;tc<4;tc++){
    bfr[tc][0] = *(const short8*)(Rt + (size_t)(16*tc + c)*sR + 8*q);
    bfr[tc][1] = *(const short8*)(Rt + (size_t)(16*tc + c)*sR + 32 + 8*q);
  }
  #pragma unroll
  for(int mt=0;mt<4;mt++){
    short8 a0 = *(const short8*)(L + (size_t)(16*mt + c)*sL + 8*q);
    short8 a1 = *(const short8*)(L + (size_t)(16*mt + c)*sL + 32 + 8*q);
    #pragma unroll
    for(int tc=0;tc<4;tc++){
      f32x4 v = out[mt][tc];
      v = __builtin_amdgcn_mfma_f32_16x16x32_bf16(a0, bfr[tc][0], v, 0, 0, 0);
      v = __builtin_amdgcn_mfma_f32_16x16x32_bf16(a1, bfr[tc][1], v, 0, 0, 0);
      out[mt][tc] = v;
    }
  }
}

// ---------------- NS body, SINGLE WAVE (no __syncthreads anywhere) --------------------------
// Round-8 PMC: the 4-wave ns tail ran ~47us at 0.4% occupancy (36 barriers x full waitcnt
// drain). One wave needs no barriers: LDS ops from a wave execute in issue order.
// Identical arithmetic/tiling (mt replaces wv); v0/vi maxes via exact shfl butterflies.
#define TTS 64
__device__ void ns_body_w(int n, char* smem, const float* __restrict__ qland,
                          const float* __restrict__ kland, float* __restrict__ KinvT){
  u16* Kb  = (u16*)(smem + 0);
  u16* Vb  = (u16*)(smem + 9216);
  u16* Vt  = (u16*)(smem + 18432);
  u16* KVb = (u16*)(smem + 27648);
  u16* KVt = (u16*)(smem + 36864);
  u16* Tt  = (u16*)(smem + 46080);         // stride 64, 8192 B -> end 54272
  float* sS = (float*)(smem + 27648);      // 64x66 f32 = 16896, aliases KVb/KVt (dead then)
  const int lane = threadIdx.x;            // 0..63 (caller guards)
  const int q = (lane>>4)&3, c = lane&15;
  const float* qb = qland + (size_t)n*LND*EDIM;
  const float* kb = kland + (size_t)n*LND*EDIM;
  f32x4 acc[4][4];
  #pragma unroll
  for(int mt=0;mt<4;mt++)
    #pragma unroll
    for(int tc=0;tc<4;tc++){ acc[mt][tc][0]=0.f; acc[mt][tc][1]=0.f; acc[mt][tc][2]=0.f; acc[mt][tc][3]=0.f; }
  // ---- k2 = (q_land/s) @ (k_land/s)^T over E=256, 64-col chunks ----
  for(int e0=0;e0<EDIM;e0+=64){
    const float* qp = qb + (size_t)lane*EDIM + e0;
    const float* kp = kb + (size_t)lane*EDIM + e0;
    u16* qd = &KVb[lane*NS2];
    u16* kd = &KVt[lane*NS2];
    #pragma unroll
    for(int j=0;j<64;j+=4){
      float4 qv = *(const float4*)(qp+j);
      float4 kv = *(const float4*)(kp+j);
      ushort4 qo, ko;
      qo.x=f2bf(qv.x); qo.y=f2bf(qv.y); qo.z=f2bf(qv.z); qo.w=f2bf(qv.w);
      ko.x=f2bf(kv.x); ko.y=f2bf(kv.y); ko.z=f2bf(kv.z); ko.w=f2bf(kv.w);
      *(ushort4*)(qd+j) = qo;
      *(ushort4*)(kd+j) = ko;
    }
    ns_mm_w(KVb, NS2, KVt, NS2, q, c, acc);
  }
  // ---- S tiles -> sS (aliases KVb/KVt; their reads precede in program order) ----
  #pragma unroll
  for(int mt=0;mt<4;mt++)
    #pragma unroll
    for(int tc=0;tc<4;tc++){
      int col = 16*tc + c, row0 = 16*mt + 4*q;
      sS[(row0+0)*66+col] = acc[mt][tc][0];
      sS[(row0+1)*66+col] = acc[mt][tc][1];
      sS[(row0+2)*66+col] = acc[mt][tc][2];
      sS[(row0+3)*66+col] = acc[mt][tc][3];
    }
  // ---- column softmax (j = lane), Kb = softmax(S) bf16 ----
  float sc;
  {
    int j = lane;
    float m = -1e30f;
    for(int i=0;i<64;i++) m = fmaxf(m, sS[i*66+j]);
    float ssum = 0.f;
    for(int i=0;i<64;i++) ssum += __expf(sS[i*66+j]-m);
    float inv = 1.f/ssum, cs = 0.f;
    for(int i=0;i<64;i++){
      float kv = __expf(sS[i*66+j]-m)*inv;
      cs += fabsf(kv);
      Kb[i*NS2+j] = f2bf(kv);
    }
    float v0 = cs;
    #pragma unroll
    for(int o=32;o;o>>=1) v0 = fmaxf(v0, __shfl_xor(v0, o));
    float rs = 0.f;
    for(int jj=0;jj<64;jj++) rs += fabsf(bf2f(Kb[lane*NS2+jj]));
    float vi = rs;
    #pragma unroll
    for(int o=32;o;o>>=1) vi = fmaxf(vi, __shfl_xor(vi, o));
    sc = 1.f/(v0*vi);
  }
  // ---- V0 = K^T * sc : Vb[i][j] = Kb[j][i]*sc, Vt = Vb^T (lane = i) ----
  for(int jj=0;jj<64;jj++){
    u16 bvv = f2bf(bf2f(Kb[jj*NS2+lane])*sc);
    Vb[lane*NS2+jj] = bvv;
    Vt[jj*NS2+lane] = bvv;
  }
  // ---- 6 Newton-Schulz iterations, all single-wave ----
  f32x4 r[4][4];
  for(int it=0; it<6; it++){
    // M1: KV = K @ V   (B^T = Vt) -> KVb (row-major) + KVt (col-major)
    #pragma unroll
    for(int mt=0;mt<4;mt++)
      #pragma unroll
      for(int tc=0;tc<4;tc++){ r[mt][tc][0]=0.f; r[mt][tc][1]=0.f; r[mt][tc][2]=0.f; r[mt][tc][3]=0.f; }
    ns_mm_w(Kb, NS2, Vt, NS2, q, c, r);
    #pragma unroll
    for(int mt=0;mt<4;mt++)
      #pragma unroll
      for(int tc=0;tc<4;tc++){
        int col = 16*tc + c, row0 = 16*mt + 4*q;
        ushort4 pk;
        pk.x = f2bf(r[mt][tc][0]); pk.y = f2bf(r[mt][tc][1]);
        pk.z = f2bf(r[mt][tc][2]); pk.w = f2bf(r[mt][tc][3]);
        KVb[(row0+0)*NS2+col] = pk.x; KVb[(row0+1)*NS2+col] = pk.y;
        KVb[(row0+2)*NS2+col] = pk.z; KVb[(row0+3)*NS2+col] = pk.w;
        *(ushort4*)&KVt[(size_t)col*NS2 + row0] = pk;
      }
    // M2: r = KV @ KV ; Tt = (7KV - r)^T
    #pragma unroll
    for(int mt=0;mt<4;mt++)
      #pragma unroll
      for(int tc=0;tc<4;tc++){ r[mt][tc][0]=0.f; r[mt][tc][1]=0.f; r[mt][tc][2]=0.f; r[mt][tc][3]=0.f; }
    ns_mm_w(KVb, NS2, KVt, NS2, q, c, r);
    #pragma unroll
    for(int mt=0;mt<4;mt++)
      #pragma unroll
      for(int tc=0;tc<4;tc++){
        int col = 16*tc+c, row0 = 16*mt+4*q;
        ushort4 pk;
        #pragma unroll
        for(int rr=0;rr<4;rr++){
          float kvv = bf2f(KVb[(row0+rr)*NS2+col]);
          ((u16*)&pk)[rr] = f2bf(7.f*kvv - r[mt][tc][rr]);
        }
        *(ushort4*)&Tt[(size_t)col*TTS + row0] = pk;
      }
    // M3: r = KV @ T ; T2^T = (15KV - r)^T -> KVt (KVt dead as KV^T from here)
    #pragma unroll
    for(int mt=0;mt<4;mt++)
      #pragma unroll
      for(int tc=0;tc<4;tc++){ r[mt][tc][0]=0.f; r[mt][tc][1]=0.f; r[mt][tc][2]=0.f; r[mt][tc][3]=0.f; }
    ns_mm_w(KVb, NS2, Tt, TTS, q, c, r);
    #pragma unroll
    for(int mt=0;mt<4;mt++)
      #pragma unroll
      for(int tc=0;tc<4;tc++){
        int col = 16*tc+c, row0 = 16*mt+4*q;
        ushort4 pk;
        #pragma unroll
        for(int rr=0;rr<4;rr++){
          float kvv = bf2f(KVb[(row0+rr)*NS2+col]);
          ((u16*)&pk)[rr] = f2bf(15.f*kvv - r[mt][tc][rr]);
        }
        *(ushort4*)&KVt[(size_t)col*NS2 + row0] = pk;
      }
    // M4: r = V @ T2  (B^T = KVt) ; newV = 0.25(13V - r) -> Vb, Vt (+ KinvT at it==5)
    #pragma unroll
    for(int mt=0;mt<4;mt++)
      #pragma unroll
      for(int tc=0;tc<4;tc++){ r[mt][tc][0]=0.f; r[mt][tc][1]=0.f; r[mt][tc][2]=0.f; r[mt][tc][3]=0.f; }
    ns_mm_w(Vb, NS2, KVt, NS2, q, c, r);
    #pragma unroll
    for(int mt=0;mt<4;mt++)
      #pragma unroll
      for(int tc=0;tc<4;tc++){
        int col = 16*tc+c, row0 = 16*mt+4*q;
        float nv[4]; ushort4 pk;
        #pragma unroll
        for(int rr=0;rr<4;rr++){
          float vv = bf2f(Vb[(row0+rr)*NS2+col]);
          nv[rr] = 0.25f*(13.f*vv - r[mt][tc][rr]);
          u16 bb = f2bf(nv[rr]);
          Vb[(row0+rr)*NS2+col] = bb;
          ((u16*)&pk)[rr] = bb;
        }
        *(ushort4*)&Vt[(size_t)col*NS2 + row0] = pk;
        if(it==5){
          *(float4*)&KinvT[(size_t)n*4096 + (size_t)col*64 + row0] = make_float4(nv[0],nv[1],nv[2],nv[3]);
        }
      }
  }
}

// ---------------- Z1/Z3 landmark GEMM + fused NS (blockIdx.x==64, wave 0 only) -------------
#define LGS 264   // A LDS row stride (u16): 528B, 16B aligned, bank-conflict-free
__global__ __launch_bounds__(256) void k_landgemm(const u16* __restrict__ Y, const float* __restrict__ qland,
                                                  const float* __restrict__ kland, float* __restrict__ Z1,
                                                  float* __restrict__ Z3, float* __restrict__ KinvT){
  __shared__ __align__(16) char usm[54272];
  const int z = blockIdx.y;
  if(blockIdx.x == 64){
    if((z&1)==0 && threadIdx.x < 64) ns_body_w(z>>1, usm, qland, kland, KinvT);
    return;   // waves 1-3 exit; ns path has NO barriers
  }
  u16* As = (u16*)usm;                 // [64][LGS]
  u16* BsU = (u16*)(usm + 33792);      // [2][64*64]
  const int n = z>>1, which = z&1;
  const int b0 = blockIdx.x*64;
  const float* land = (which ? qland : kland) + (size_t)n*LND*EDIM;
  const int boff = which ? 256 : 0;
  float* out = (which ? Z3 : Z1) + (size_t)n*LND*HWN;
  const u16* Yb = Y + (size_t)n*M3*HWN + boff;
  const int tid = threadIdx.x, lane = tid&63;
  const int c = tid&15, qq = (tid>>4)&3, wv = tid>>6;
  {
    int r = tid>>2, c0 = (tid&3)*64;
    const float* lp = land + (size_t)r*EDIM + c0;
    u16* dp = &As[r*LGS + c0];
    #pragma unroll
    for(int j=0;j<64;j+=4){
      float4 v = *(const float4*)(lp+j);
      ushort4 o; o.x=f2bf(v.x); o.y=f2bf(v.y); o.z=f2bf(v.z); o.w=f2bf(v.w);
      *(ushort4*)(dp+j) = o;
    }
  }
  const int srow  = wv*8 + (lane>>3);            // 0..31
  const int dslot = lane&7;
  const int sgo   = (dslot ^ (lane>>3))*8;       // row&7 == lane>>3 here
  const int rdswz = (c&7);
  f32x4 acc[4];
  #pragma unroll
  for(int nt=0;nt<4;nt++){ acc[nt][0]=0.f; acc[nt][1]=0.f; acc[nt][2]=0.f; acc[nt][3]=0.f; }
  #pragma unroll
  for(int j=0;j<2;j++){
    int r = j*32 + srow;
    gl16(Yb + (size_t)(b0+r)*M3 + sgo, BsU + r*64 + dslot*8);
  }
  __syncthreads();
  for(int ph=0; ph<4; ph++){
    const int cur = ph&1;
    if(ph<3){
      #pragma unroll
      for(int j=0;j<2;j++){
        int r = j*32 + srow;
        gl16(Yb + (size_t)(b0+r)*M3 + (ph+1)*64 + sgo, BsU + (cur^1)*4096 + r*64 + dslot*8);
      }
    }
    #pragma unroll
    for(int kt=0;kt<2;kt++){
      short8 af = *(const short8*)&As[(16*wv + c)*LGS + ph*64 + kt*32 + qq*8];
      const int rslot = ((kt*4+qq)^rdswz)*8;
      #pragma unroll
      for(int nt=0;nt<4;nt++){
        short8 bff = *(const short8*)&BsU[cur*4096 + (nt*16+c)*64 + rslot];
        acc[nt] = __builtin_amdgcn_mfma_f32_16x16x32_bf16(af, bff, acc[nt], 0, 0, 0);
      }
    }
    __syncthreads();
  }
  const int m0 = 16*wv + 4*qq;
  #pragma unroll
  for(int nt=0;nt<4;nt++){
    int col = b0 + nt*16 + c;
    out[(size_t)(m0+0)*HWN + col] = acc[nt][0];
    out[(size_t)(m0+1)*HWN + col] = acc[nt][1];
    out[(size_t)(m0+2)*HWN + col] = acc[nt][2];
    out[(size_t)(m0+3)*HWN + col] = acc[nt][3];
  }
}

// ---------------- soft1 body: softmax of Z1 over contiguous 4096 ----------------
__device__ void soft1_body(int b, char* smem, float* __restrict__ Z1){
  const int n = b>>6, j = b&63, tid = threadIdx.x;
  float* redm = (float*)smem;
  float* reds = redm + 4;
  float* base = Z1 + ((size_t)n*LND + j)*HWN;
  float v[16];
  float m = -1e30f;
  #pragma unroll
  for(int r=0;r<16;r++){ v[r] = base[r*256 + tid]; m = fmaxf(m, v[r]); }
  #pragma unroll
  for(int o=32;o;o>>=1) m = fmaxf(m, __shfl_xor(m, o));
  const int wid = tid>>6;
  if((tid&63)==0) redm[wid] = m;
  __syncthreads();
  m = fmaxf(fmaxf(redm[0],redm[1]), fmaxf(redm[2],redm[3]));
  float s = 0.f;
  #pragma unroll
  for(int r=0;r<16;r++){ v[r] = __expf(v[r]-m); s += v[r]; }
  #pragma unroll
  for(int o=32;o;o>>=1) s += __shfl_xor(s, o);
  if((tid&63)==0) reds[wid] = s;
  __syncthreads();
  s = reds[0]+reds[1]+reds[2]+reds[3];
  float inv = 1.f/s;
  #pragma unroll
  for(int r=0;r<16;r++) base[r*256 + tid] = v[r]*inv;
}

// ---------------- fused soft3 + PV GEMM (+ soft1 blocks 512-1023) ---------------------------
__global__ __launch_bounds__(256) void k_pv(const float* __restrict__ Z3, const u16* __restrict__ Y,
                                            float* __restrict__ part, float* __restrict__ Z1){
  __shared__ __align__(16) char smem[50688];
  const int bi = blockIdx.x;
  if(bi >= 512){ soft1_body(bi-512, smem, Z1); return; }
  float* Sf   = (float*)smem;              // [64][132] logits -> exp   (0..33792)
  float* sinv = (float*)(smem + 33792);    // [128] 1/sum               (33792..34304)
  u16*   Asb  = (u16*)(smem + 34304);      // [2][64][64] P bf16, XOR-swizzled (..50688)
  u16*   Vt   = (u16*)smem;                // [128 e][64 j] per phase — overlays Sf (dead)
  const int kc = bi&31, n = (bi>>5)&7, eh = bi>>8;
  const int jb = kc*128, eb = eh*128;
  const int tid = threadIdx.x, lane = tid&63;
  const int c = tid&15, qq = (tid>>4)&3, wv = tid>>6;
  const u16* Yb = Y + (size_t)n*M3*HWN;       // raw view: V[j][e] = flat[j*768 + 512 + e]
  const float* z3b = Z3 + (size_t)n*LND*HWN;
  // ---- soft3: stage logits ----
  {
    int ibase = (tid>>5)*8, j4 = (tid&31)*4;
    #pragma unroll
    for(int r=0;r<8;r++){
      int i = ibase + r;
      *(float4*)&Sf[i*132 + j4] = *(const float4*)&z3b[(size_t)i*HWN + jb + j4];
    }
  }
  __syncthreads();
  if(tid < 128){
    int j = tid;
    float m = -1e30f;
    for(int i=0;i<64;i++) m = fmaxf(m, Sf[i*132 + j]);
    float s = 0.f;
    for(int i=0;i<64;i++){ float e = __expf(Sf[i*132 + j] - m); Sf[i*132 + j] = e; s += e; }
    sinv[j] = 1.f/s;
  }
  __syncthreads();
  // ---- write P bf16 straight into swizzled A buffers (both phases) ----
  {
    int i = tid>>2, j0q = (tid&3)*32;
    const int iswz = (i&7);
    #pragma unroll
    for(int t=0;t<32;t+=4){
      int jg = j0q + t;                 // 0..127
      int phb = jg>>6, jl = jg&63;
      ushort4 o;
      o.x = f2bf(Sf[i*132 + jg+0]*sinv[jg+0]);
      o.y = f2bf(Sf[i*132 + jg+1]*sinv[jg+1]);
      o.z = f2bf(Sf[i*132 + jg+2]*sinv[jg+2]);
      o.w = f2bf(Sf[i*132 + jg+3]*sinv[jg+3]);
      *(ushort4*)&Asb[phb*4096 + i*64 + ((jl>>3)^iswz)*8 + (jl&7)] = o;
    }
  }
  __syncthreads();   // Sf dead from here; Vt may overlay it
  const int rdswz = (c&7);
  f32x4 acc[4][2];
  #pragma unroll
  for(int mt=0;mt<4;mt++)
    #pragma unroll
    for(int nt=0;nt<2;nt++){ acc[mt][nt][0]=0.f; acc[mt][nt][1]=0.f; acc[mt][nt][2]=0.f; acc[mt][nt][3]=0.f; }
  for(int ph=0; ph<2; ph++){
    #pragma unroll
    for(int rep=0; rep<4; rep++){
      int jl = (tid>>4) + 16*rep;                       // 0..63
      int ec = (tid&15)*8;                              // 0..120
      uint4 U = *(const uint4*)&Yb[(size_t)(jb+ph*64+jl)*M3 + 512 + eb + ec];
      const u16* uv = (const u16*)&U;
      #pragma unroll
      for(int k=0;k<8;k++){
        int e = ec+k;
        int slot = ((jl>>3) ^ (e&7) ^ ((e>>3)&7)) & 7;
        Vt[e*64 + slot*8 + (jl&7)] = uv[k];
      }
    }
    __syncthreads();
    #pragma unroll
    for(int kt=0;kt<2;kt++){
      const int rslotA = ((kt*4+qq)^rdswz)*8;
      short8 af[4];
      #pragma unroll
      for(int mt=0;mt<4;mt++) af[mt] = *(const short8*)&Asb[ph*4096 + (mt*16+c)*64 + rslotA];
      #pragma unroll
      for(int nt=0;nt<2;nt++){
        int e = wv*32 + nt*16 + c;
        int slotB = ((kt*4+qq) ^ (e&7) ^ ((e>>3)&7)) & 7;
        short8 bf_ = *(const short8*)&Vt[e*64 + slotB*8];
        #pragma unroll
        for(int mt=0;mt<4;mt++)
          acc[mt][nt] = __builtin_amdgcn_mfma_f32_16x16x32_bf16(af[mt], bf_, acc[mt][nt], 0, 0, 0);
      }
    }
    __syncthreads();
  }
  float* pb = part + ((size_t)n*32 + kc)*LND*EDIM + eb;
  #pragma unroll
  for(int mt=0;mt<4;mt++){
    int row0 = mt*16 + 4*qq;
    #pragma unroll
    for(int nt=0;nt<2;nt++){
      int e = wv*32 + nt*16 + c;
      pb[(size_t)(row0+0)*EDIM + e] = acc[mt][nt][0];
      pb[(size_t)(row0+1)*EDIM + e] = acc[mt][nt][1];
      pb[(size_t)(row0+2)*EDIM + e] = acc[mt][nt][2];
      pb[(size_t)(row0+3)*EDIM + e] = acc[mt][nt][3];
    }
  }
}

// ---------------- C2T[n][e][j] (bf16) = (Kinv @ sum_kc part)[j][e], fused fred+c2 ----------
__global__ __launch_bounds__(256) void k_c2(const float* __restrict__ KinvT, const float* __restrict__ part,
                                            u16* __restrict__ C2T){
  const int eb = blockIdx.x*64, n = blockIdx.y, tid = threadIdx.x;
  __shared__ float KT[64][68];
  __shared__ float Bs2[64][68];
  __shared__ u16 Ct[64*72];
  {
    int l = tid>>2, o16 = (tid&3)*16;
    const float* kp = KinvT + (size_t)n*4096 + l*64 + o16;
    #pragma unroll
    for(int t=0;t<16;t+=4) *(float4*)&KT[l][o16+t] = *(const float4*)(kp+t);
    // fused k_fred: B3[l][eb+o16..+16] = sum_kc part[n][kc][l][...]
    const float* pp = part + (size_t)n*32*16384 + (size_t)l*256 + eb + o16;
    float4 s0 = {0,0,0,0}, s1 = {0,0,0,0}, s2 = {0,0,0,0}, s3 = {0,0,0,0};
    for(int kc=0;kc<32;kc++){
      const float* b = pp + (size_t)kc*16384;
      float4 v0 = *(const float4*)(b);
      float4 v1 = *(const float4*)(b+4);
      float4 v2 = *(const float4*)(b+8);
      float4 v3 = *(const float4*)(b+12);
      s0.x+=v0.x; s0.y+=v0.y; s0.z+=v0.z; s0.w+=v0.w;
      s1.x+=v1.x; s1.y+=v1.y; s1.z+=v1.z; s1.w+=v1.w;
      s2.x+=v2.x; s2.y+=v2.y; s2.z+=v2.z; s2.w+=v2.w;
      s3.x+=v3.x; s3.y+=v3.y; s3.z+=v3.z; s3.w+=v3.w;
    }
    *(float4*)&Bs2[l][o16+0]  = s0;
    *(float4*)&Bs2[l][o16+4]  = s1;
    *(float4*)&Bs2[l][o16+8]  = s2;
    *(float4*)&Bs2[l][o16+12] = s3;
  }
  __syncthreads();
  const int j0 = (tid>>4)*4, u0 = (tid&15)*4;
  float acc[4][4] = {};
  #pragma unroll 8
  for(int l=0;l<64;l++){
    f32x4 a = *(f32x4*)&KT[l][j0];
    f32x4 b = *(f32x4*)&Bs2[l][u0];
    #pragma unroll
    for(int s=0;s<4;s++)
      #pragma unroll
      for(int u=0;u<4;u++) acc[s][u] += a[s]*b[u];
  }
  // transpose to bf16 [e][j] via LDS, then coalesced global write
  #pragma unroll
  for(int s=0;s<4;s++)
    #pragma unroll
    for(int u=0;u<4;u++)
      Ct[(u0+u)*72 + j0+s] = f2bf(acc[s][u]);
  __syncthreads();
  {
    int e = tid>>2, j16 = (tid&3)*16;
    u16* op = C2T + ((size_t)n*256 + eb + e)*64 + j16;
    #pragma unroll
    for(int t=0;t<16;t+=4)
      *(ushort4*)(op+t) = *(const ushort4*)&Ct[e*72 + j16 + t];
  }
}

// ---------------- out[i][e] = sum_j Z1[j][i]*C2[j][e] + v[i][e]; MFMA, OM bf16 --------------
__global__ __launch_bounds__(256) void k_out(const float* __restrict__ Z1, const u16* __restrict__ C2T,
                                             const u16* __restrict__ Y, u16* __restrict__ OM){
  __shared__ __align__(16) u16 Cs[256*64];    // [256 e][64 j], gl16-swizzled
  __shared__ __align__(16) u16 Zt[64*72];     // [64 i][72 j]
  const int ib = blockIdx.x*64, n = blockIdx.y;
  const int tid = threadIdx.x, lane = tid&63;
  const int c = tid&15, qq = (tid>>4)&3, wv = tid>>6;
  const int srow  = wv*8 + (lane>>3);
  const int dslot = lane&7;
  const int sgo   = (dslot ^ (lane>>3))*8;
  const int rdswz = (c&7);
  const u16* cb = C2T + (size_t)n*256*64;
  #pragma unroll
  for(int j=0;j<8;j++){
    int r = j*32 + srow;
    gl16(cb + (size_t)r*64 + sgo, &Cs[r*64 + dslot*8]);
  }
  {
    int j = tid>>2, i16 = (tid&3)*16;
    const float* zp = Z1 + ((size_t)n*LND + j)*HWN + ib + i16;
    #pragma unroll
    for(int t=0;t<16;t+=4){
      float4 v = *(const float4*)(zp+t);
      Zt[(i16+t+0)*72 + j] = f2bf(v.x);
      Zt[(i16+t+1)*72 + j] = f2bf(v.y);
      Zt[(i16+t+2)*72 + j] = f2bf(v.z);
      Zt[(i16+t+3)*72 + j] = f2bf(v.w);
    }
  }
  __syncthreads();
  f32x4 acc[4][4];
  #pragma unroll
  for(int mt=0;mt<4;mt++)
    #pragma unroll
    for(int nt=0;nt<4;nt++){ acc[mt][nt][0]=0.f; acc[mt][nt][1]=0.f; acc[mt][nt][2]=0.f; acc[mt][nt][3]=0.f; }
  #pragma unroll
  for(int kt=0;kt<2;kt++){
    const int rslot = ((kt*4+qq)^rdswz)*8;
    short8 af[4], bf_[4];
    #pragma unroll
    for(int mt=0;mt<4;mt++) af[mt] = *(const short8*)&Cs[(wv*64+mt*16+c)*64 + rslot];
    #pragma unroll
    for(int nt=0;nt<4;nt++) bf_[nt] = *(const short8*)&Zt[(nt*16+c)*72 + kt*32 + qq*8];
    #pragma unroll
    for(int mt=0;mt<4;mt++)
      #pragma unroll
      for(int nt=0;nt<4;nt++)
        acc[mt][nt] = __builtin_amdgcn_mfma_f32_16x16x32_bf16(af[mt], bf_[nt], acc[mt][nt], 0, 0, 0);
  }
  // epilogue: e = wv*64 + mt*16 + 4*qq (+r), i = ib + nt*16 + c ; ushort4 V-add + store
  const u16* Yb = Y + (size_t)n*M3*HWN;
  u16* ob = OM + (size_t)n*HWN*EDIM;
  #pragma unroll
  for(int mt=0;mt<4;mt++){
    int e = wv*64 + mt*16 + 4*qq;
    #pragma unroll
    for(int nt=0;nt<4;nt++){
      int i = ib + nt*16 + c;
      ushort4 V4 = *(const ushort4*)(Yb + (size_t)i*M3 + 512 + e);
      ushort4 o;
      o.x = f2bf(acc[mt][nt][0] + bf2f(V4.x));
      o.y = f2bf(acc[mt][nt][1] + bf2f(V4.y));
      o.z = f2bf(acc[mt][nt][2] + bf2f(V4.z));
      o.w = f2bf(acc[mt][nt][3] + bf2f(V4.w));
      *(ushort4*)(ob + (size_t)i*EDIM + e) = o;
    }
  }
}

// ---------------- proj GEMM 128x128xK256; B read directly from OM raw [e'][p'] view ---------
__global__ __launch_bounds__(256) void k_proj(const u16* __restrict__ Wb, const u16* __restrict__ OM,
                                              const float* __restrict__ bias, float* __restrict__ out){
  __shared__ __align__(16) u16 As[128*64];
  __shared__ __align__(16) u16 Bt[128*64];    // [128 p][64 e'] slot-XOR layout
  const int bi = blockIdx.x;
  const int n = bi&7, rem = bi>>3;
  const int ch0 = (rem&1)*128, p0 = (rem>>1)*128;
  const int tid = threadIdx.x, lane = tid&63;
  const int c = tid&15, qq = (tid>>4)&3, w4 = tid>>6;
  const int wr0 = (w4&1)*64, wc0 = (w4>>1)*64;
  const u16* omb = OM + (size_t)n*HWN*EDIM;   // flat, viewed [256 e'][4096 p']
  const u16* wb = Wb + (size_t)ch0*EDIM;
  f32x4 acc[4][4];
  #pragma unroll
  for(int mt=0;mt<4;mt++)
    #pragma unroll
    for(int nt=0;nt<4;nt++){ acc[mt][nt][0]=0.f; acc[mt][nt][1]=0.f; acc[mt][nt][2]=0.f; acc[mt][nt][3]=0.f; }
  const int srow  = w4*8 + (lane>>3);
  const int dslot = lane&7;
  const int sgo   = (dslot ^ (lane>>3))*8;
  const int rdswz = (c&7);
  for(int ph=0; ph<4; ph++){
    #pragma unroll
    for(int j=0;j<4;j++){
      int r = j*32 + srow;
      gl16(wb + (size_t)r*EDIM + ph*64 + sgo, &As[r*64 + dslot*8]);
    }
    #pragma unroll
    for(int rep=0; rep<4; rep++){
      int ee = (tid>>4) + 16*rep;                       // 0..63 (e' within phase)
      int pc = (tid&15)*8;                              // 0..120
      uint4 U = *(const uint4*)&omb[(size_t)(ph*64+ee)*HWN + p0 + pc];
      const u16* uv = (const u16*)&U;
      #pragma unroll
      for(int k=0;k<8;k++){
        int p = pc+k;
        int slot = ((ee>>3) ^ (p&7) ^ ((p>>3)&7)) & 7;
        Bt[p*64 + slot*8 + (ee&7)] = uv[k];
      }
    }
    __syncthreads();
    #pragma unroll
    for(int kt=0;kt<2;kt++){
      const int rslot = ((kt*4+qq)^rdswz)*8;
      short8 af[4], bff[4];
      #pragma unroll
      for(int mt=0;mt<4;mt++) af[mt] = *(const short8*)&As[(wr0+mt*16+c)*64 + rslot];
      #pragma unroll
      for(int nt=0;nt<4;nt++){
        int p = wc0 + nt*16 + c;
        int slotB = ((kt*4+qq) ^ (p&7) ^ ((p>>3)&7)) & 7;
        bff[nt] = *(const short8*)&Bt[p*64 + slotB*8];
      }
      #pragma unroll
      for(int mt=0;mt<4;mt++)
        #pragma unroll
        for(int nt=0;nt<4;nt++)
          acc[mt][nt] = __builtin_amdgcn_mfma_f32_16x16x32_bf16(af[mt], bff[nt], acc[mt][nt], 0, 0, 0);
    }
    __syncthreads();
  }
  float* ob = out + (size_t)n*EDIM*HWN;
  #pragma unroll
  for(int mt=0;mt<4;mt++){
    int chb = ch0 + wr0 + mt*16 + 4*qq;
    float b0 = bias[chb], b1 = bias[chb+1], b2 = bias[chb+2], b3 = bias[chb+3];
    #pragma unroll
    for(int nt=0;nt<4;nt++){
      int p = p0 + wc0 + nt*16 + c;
      float* yp = ob + (size_t)chb*HWN + p;
      yp[0]             = acc[mt][nt][0]+b0;
      yp[HWN]           = acc[mt][nt][1]+b1;
      yp[2*(size_t)HWN] = acc[mt][nt][2]+b2;
      yp[3*(size_t)HWN] = acc[mt][nt][3]+b3;
    }
  }
}

extern "C" void kernel_launch(void* const* d_in, const int* in_sizes, int n_in,
                              void* d_out, int out_size, void* d_ws, size_t ws_size,
                              hipStream_t stream){
  (void)out_size; (void)ws_size;
  const float* x     = (const float*)d_in[0];
  const float* w_qkv = (const float*)d_in[1];
  const float* b_qkv = (const float*)d_in[2];
  const float* w_out = (const float*)d_in[3];
  const float* b_out = (const float*)d_in[4];
  for(int i=0;i<n_in;i++){
    switch(in_sizes[i]){
      case 8388608: x     = (const float*)d_in[i]; break;
      case 196608:  w_qkv = (const float*)d_in[i]; break;
      case 768:     b_qkv = (const float*)d_in[i]; break;
      case 65536:   w_out = (const float*)d_in[i]; break;
      case 256:     b_out = (const float*)d_in[i]; break;
      default: break;
    }
  }
  float* out = (float*)d_out;
  char* ws = (char*)d_ws;

  u16*   Y     = (u16*)(ws + 0);              // 50,331,648 B  bf16 [8][768*4096]
  float* qland = (float*)(ws + 50331648);
  float* kland = (float*)(ws + 50855936);
  float* Z1    = (float*)(ws + 51380224);
  float* Z3    = (float*)(ws + 59768832);
  float* KinvT = (float*)(ws + 68157440);
  float* part  = (float*)(ws + 68288512);     // 16 MB region (was Xt -> part)
  u16*   Xt    = (u16*)(ws + 68288512);
  u16*   C2T   = (u16*)(ws + 85065728);       // bf16 [8][256 e][64 j] = 256 KB
  u16*   OM    = (u16*)(ws + 86114304);       // 16 MB bf16
  // Wqb overlaps Z3 (Z3 written by k_landgemm AFTER k_qkv consumes Wqb — stream-ordered safe)
  u16*   Wqb   = (u16*)(ws + 59768832);       // 393,216 B bf16 [768][256]
  u16*   Wob   = (u16*)(ws + 102891520);      // 131,072 B bf16 [256][256] (persists to k_proj)

  k_prep    <<<dim3(2056),   256, 0, stream>>>(x, Xt, w_qkv, w_out, Wqb, Wob);
  k_qkv     <<<dim3(1536),   256, 0, stream>>>(Wqb, Xt, b_qkv, Y);
  k_land    <<<dim3(64,8),   256, 0, stream>>>(Y, qland, kland);
  k_landgemm<<<dim3(65,16),  256, 0, stream>>>(Y, qland, kland, Z1, Z3, KinvT);
  k_pv      <<<dim3(1024),   256, 0, stream>>>(Z3, Y, part, Z1);
  k_c2      <<<dim3(4,8),    256, 0, stream>>>(KinvT, part, C2T);
  k_out     <<<dim3(64,8),   256, 0, stream>>>(Z1, C2T, Y, OM);
  k_proj    <<<dim3(512),    256, 0, stream>>>(Wob, OM, b_out, out);
}

// Round 10
// 204.584 us; speedup vs baseline: 1.1300x; 1.1300x over previous
//
#include <hip/hip_runtime.h>
#include <hip/hip_bf16.h>

typedef unsigned short u16;
typedef __attribute__((ext_vector_type(4))) float f32x4;
typedef __attribute__((ext_vector_type(8))) short short8;

#define NB   8
#define CIN  256
#define EDIM 256
#define M3   768
#define HWN  4096
#define LND  64
#define NS2  72    // NS LDS row stride (bf16 elems): 144B, 16B aligned

__device__ __forceinline__ float bf2f(u16 u){ return __uint_as_float(((unsigned)u)<<16); }
__device__ __forceinline__ u16 f2bf(float f){ __hip_bfloat16 h = __float2bfloat16(f); return *reinterpret_cast<u16*>(&h); }
__device__ __forceinline__ void bf2x2(unsigned u, float &lo, float &hi){
  lo = __uint_as_float(u<<16);
  hi = __uint_as_float(u & 0xffff0000u);
}

typedef __attribute__((address_space(1))) unsigned as1_uint;
typedef __attribute__((address_space(3))) unsigned as3_uint;
// async global->LDS, 16B per lane; dest must be wave-uniform base + lane*16
__device__ __forceinline__ void gl16(const void* g, void* l){
  __builtin_amdgcn_global_load_lds((const as1_uint*)g, (as3_uint*)l, 16, 0, 0);
}

// ---------------- prep: Xt[n][p][c] (bf16) = transpose of X[n][c][p] (fp32) ----------------
// blocks >= 2048: convert w_qkv / w_out to bf16 (once, instead of per GEMM block)
__global__ __launch_bounds__(256) void k_prep(const float* __restrict__ x, u16* __restrict__ Xt,
                                              const float* __restrict__ wq, const float* __restrict__ wo,
                                              u16* __restrict__ Wqb, u16* __restrict__ Wob){
  const int bi = blockIdx.x;
  const int tid = threadIdx.x;
  if(bi >= 2048){
    int ti = (bi-2048)*256 + tid;          // 0..2047
    const float* src; u16* dst;
    if(ti < 1536){ src = wq + (size_t)ti*128;        dst = Wqb + (size_t)ti*128; }
    else         { src = wo + (size_t)(ti-1536)*128; dst = Wob + (size_t)(ti-1536)*128; }
    #pragma unroll
    for(int t=0;t<128;t+=8){
      float4 v0 = *(const float4*)(src+t);
      float4 v1 = *(const float4*)(src+t+4);
      ushort4 o0, o1;
      o0.x=f2bf(v0.x); o0.y=f2bf(v0.y); o0.z=f2bf(v0.z); o0.w=f2bf(v0.w);
      o1.x=f2bf(v1.x); o1.y=f2bf(v1.y); o1.z=f2bf(v1.z); o1.w=f2bf(v1.w);
      *(ushort4*)(dst+t)   = o0;
      *(ushort4*)(dst+t+4) = o1;
    }
    return;
  }
  __shared__ float Ts[64*65];
  const int n = bi>>8, rem = bi&255, ct = rem>>6, pt = rem&63;
  const int c0 = ct*64, p0 = pt*64;
  {
    int cc = tid>>2, pj = (tid&3)*16;
    const float* xp = x + (size_t)n*CIN*HWN + (size_t)(c0+cc)*HWN + p0 + pj;
    #pragma unroll
    for(int j=0;j<16;j++) Ts[cc*65 + pj + j] = xp[j];
  }
  __syncthreads();
  {
    int pp = tid>>2, ej = (tid&3)*16;
    u16* op = Xt + ((size_t)n*HWN + p0 + pp)*CIN + c0 + ej;
    ushort4 o[4];
    #pragma unroll
    for(int j=0;j<16;j++) ((u16*)o)[j] = f2bf(Ts[(ej+j)*65 + pp]);
    *(ushort4*)(op+0)  = o[0];
    *(ushort4*)(op+4)  = o[1];
    *(ushort4*)(op+8)  = o[2];
    *(ushort4*)(op+12) = o[3];
  }
}

// ---------------- QKV GEMM 128x128xK256 bf16 MFMA, global_load_lds + XOR swizzle ------------
__global__ __launch_bounds__(256) void k_qkv(const u16* __restrict__ Wb, const u16* __restrict__ Xt,
                                             const float* __restrict__ bias, u16* __restrict__ Y){
  __shared__ __align__(16) u16 As[128*64];
  __shared__ __align__(16) u16 Bs[128*64];
  const int bi = blockIdx.x;
  const int n = bi&7, rem = bi>>3;
  const int ch0 = (rem%6)*128, p0 = (rem/6)*128;
  const int tid = threadIdx.x, lane = tid&63;
  const int c = tid&15, qq = (tid>>4)&3, w4 = tid>>6;
  const int wr0 = (w4&1)*64, wc0 = (w4>>1)*64;
  const u16* xb = Xt + ((size_t)n*HWN + p0)*CIN;
  const u16* wb = Wb + (size_t)ch0*CIN;
  f32x4 acc[4][4];
  #pragma unroll
  for(int mt=0;mt<4;mt++)
    #pragma unroll
    for(int nt=0;nt<4;nt++){ acc[mt][nt][0]=0.f; acc[mt][nt][1]=0.f; acc[mt][nt][2]=0.f; acc[mt][nt][3]=0.f; }
  const int srow  = w4*8 + (lane>>3);
  const int dslot = lane&7;
  const int sgo   = (dslot ^ (lane>>3))*8;       // swizzled source u16 offset within row-chunk
  const int rdswz = (c&7);                        // read-side row&7
  for(int ph=0; ph<4; ph++){
    #pragma unroll
    for(int j=0;j<4;j++){
      int r = j*32 + srow;
      gl16(wb + (size_t)r*CIN + ph*64 + sgo, &As[r*64 + dslot*8]);
    }
    #pragma unroll
    for(int j=0;j<4;j++){
      int r = j*32 + srow;
      gl16(xb + (size_t)r*CIN + ph*64 + sgo, &Bs[r*64 + dslot*8]);
    }
    __syncthreads();
    #pragma unroll
    for(int kt=0;kt<2;kt++){
      short8 af[4], bff[4];
      const int rslot = ((kt*4+qq)^rdswz)*8;
      #pragma unroll
      for(int mt=0;mt<4;mt++) af[mt]  = *(const short8*)&As[(wr0+mt*16+c)*64 + rslot];
      #pragma unroll
      for(int nt=0;nt<4;nt++) bff[nt] = *(const short8*)&Bs[(wc0+nt*16+c)*64 + rslot];
      #pragma unroll
      for(int mt=0;mt<4;mt++)
        #pragma unroll
        for(int nt=0;nt<4;nt++)
          acc[mt][nt] = __builtin_amdgcn_mfma_f32_16x16x32_bf16(af[mt], bff[nt], acc[mt][nt], 0, 0, 0);
    }
    __syncthreads();
  }
  u16* Yb = Y + (size_t)n*M3*HWN;
  #pragma unroll
  for(int mt=0;mt<4;mt++){
    int chb = ch0 + wr0 + mt*16 + 4*qq;
    float b0 = bias[chb], b1 = bias[chb+1], b2 = bias[chb+2], b3 = bias[chb+3];
    #pragma unroll
    for(int nt=0;nt<4;nt++){
      int p = p0 + wc0 + nt*16 + c;
      u16* yp = Yb + (size_t)chb*HWN + p;
      yp[0]             = f2bf(acc[mt][nt][0]+b0);
      yp[HWN]           = f2bf(acc[mt][nt][1]+b1);
      yp[2*(size_t)HWN] = f2bf(acc[mt][nt][2]+b2);
      yp[3*(size_t)HWN] = f2bf(acc[mt][nt][3]+b3);
    }
  }
}

// ---------------- landmarks ----------------
__global__ void k_land(const u16* __restrict__ Y, float* __restrict__ qland, float* __restrict__ kland){
  const int l = blockIdx.x, n = blockIdx.y, e = threadIdx.x;
  const u16* base = Y + (size_t)n*M3*HWN;
  float qs=0.f, ks=0.f;
  #pragma unroll 8
  for(int m=0;m<64;m++){
    size_t off = (size_t)(l*64+m)*M3;
    qs += bf2f(base[off+e]);
    ks += bf2f(base[off+256+e]);
  }
  qland[((size_t)n*LND+l)*EDIM+e] = qs*(1.f/4096.f);
  kland[((size_t)n*LND+l)*EDIM+e] = ks*(1.f/4096.f);
}

// ---------------- NS 64x64 matmul via bf16 MFMA (per-operand LDS row stride) ----------------
__device__ __forceinline__ void ns_mm2(const u16* L, int sL, const u16* Rt, int sR,
                                       int wv, int q, int c, f32x4 r4[4]){
  short8 a0 = *(const short8*)(L + (size_t)(16*wv + c)*sL + 8*q);
  short8 a1 = *(const short8*)(L + (size_t)(16*wv + c)*sL + 32 + 8*q);
  #pragma unroll
  for(int tc=0;tc<4;tc++){
    f32x4 acc = {0.f,0.f,0.f,0.f};
    short8 b0 = *(const short8*)(Rt + (size_t)(16*tc + c)*sR + 8*q);
    short8 b1 = *(const short8*)(Rt + (size_t)(16*tc + c)*sR + 32 + 8*q);
    acc = __builtin_amdgcn_mfma_f32_16x16x32_bf16(a0, b0, acc, 0, 0, 0);
    acc = __builtin_amdgcn_mfma_f32_16x16x32_bf16(a1, b1, acc, 0, 0, 0);
    r4[tc] = acc;
  }
}

// ---------------- NS body (k2 + Newton-Schulz pseudo-inverse), 4-wave round-8 version -------
#define TTS 64
__device__ void ns_body(int n, char* smem, const float* __restrict__ qland,
                        const float* __restrict__ kland, float* __restrict__ KinvT){
  u16* Kb  = (u16*)(smem + 0);
  u16* Vb  = (u16*)(smem + 9216);
  u16* Vt  = (u16*)(smem + 18432);
  u16* KVb = (u16*)(smem + 27648);
  u16* KVt = (u16*)(smem + 36864);
  u16* Tt  = (u16*)(smem + 46080);         // stride 64, 8192 B -> end 54272
  float* sS   = (float*)(smem + 27648);    // 64x66 f32 = 16896, aliases KVb/KVt
  float* sred = (float*)(smem + 44544);    // 520 B, ends 45064 < 46080
  const int tid = threadIdx.x;
  const int wv = tid>>6, q = (tid>>4)&3, c = tid&15;
  const float* qb = qland + (size_t)n*LND*EDIM;
  const float* kb = kland + (size_t)n*LND*EDIM;
  f32x4 acc[4];
  #pragma unroll
  for(int t=0;t<4;t++){ acc[t][0]=0.f; acc[t][1]=0.f; acc[t][2]=0.f; acc[t][3]=0.f; }
  for(int e0=0;e0<EDIM;e0+=64){
    __syncthreads();
    {
      int row = tid>>2, c0 = (tid&3)*16;
      const float* qp = qb + (size_t)row*EDIM + e0 + c0;
      const float* kp = kb + (size_t)row*EDIM + e0 + c0;
      u16* qd = &KVb[row*NS2 + c0];
      u16* kd = &KVt[row*NS2 + c0];
      #pragma unroll
      for(int j=0;j<16;j+=4){
        float4 qv = *(const float4*)(qp+j);
        float4 kv = *(const float4*)(kp+j);
        ushort4 qo, ko;
        qo.x=f2bf(qv.x); qo.y=f2bf(qv.y); qo.z=f2bf(qv.z); qo.w=f2bf(qv.w);
        ko.x=f2bf(kv.x); ko.y=f2bf(kv.y); ko.z=f2bf(kv.z); ko.w=f2bf(kv.w);
        *(ushort4*)(qd+j) = qo;
        *(ushort4*)(kd+j) = ko;
      }
    }
    __syncthreads();
    {
      short8 a0 = *(const short8*)&KVb[(16*wv+c)*NS2 + 8*q];
      short8 a1 = *(const short8*)&KVb[(16*wv+c)*NS2 + 32 + 8*q];
      #pragma unroll
      for(int tc=0;tc<4;tc++){
        short8 b0 = *(const short8*)&KVt[(16*tc+c)*NS2 + 8*q];
        short8 b1 = *(const short8*)&KVt[(16*tc+c)*NS2 + 32 + 8*q];
        acc[tc] = __builtin_amdgcn_mfma_f32_16x16x32_bf16(a0, b0, acc[tc], 0, 0, 0);
        acc[tc] = __builtin_amdgcn_mfma_f32_16x16x32_bf16(a1, b1, acc[tc], 0, 0, 0);
      }
    }
  }
  __syncthreads();   // KVb/KVt reads done everywhere before sS (alias) is written
  #pragma unroll
  for(int tc=0;tc<4;tc++){
    int col = 16*tc + c, row0 = 16*wv + 4*q;
    sS[(row0+0)*66+col] = acc[tc][0];
    sS[(row0+1)*66+col] = acc[tc][1];
    sS[(row0+2)*66+col] = acc[tc][2];
    sS[(row0+3)*66+col] = acc[tc][3];
  }
  __syncthreads();
  if(tid < 64){
    int j = tid;
    float m = -1e30f;
    for(int i=0;i<64;i++) m = fmaxf(m, sS[i*66+j]);
    float ssum = 0.f;
    for(int i=0;i<64;i++) ssum += __expf(sS[i*66+j]-m);
    float inv = 1.f/ssum, cs = 0.f;
    for(int i=0;i<64;i++){
      float kv = __expf(sS[i*66+j]-m)*inv;
      cs += fabsf(kv);
      Kb[i*NS2+j] = f2bf(kv);
    }
    sred[j] = cs;
  }
  __syncthreads();
  if(tid < 64){
    int i = tid; float rs = 0.f;
    for(int j=0;j<64;j++) rs += fabsf(bf2f(Kb[i*NS2+j]));
    sred[64+i] = rs;
  }
  __syncthreads();
  if(tid == 0){
    float v0=-1e30f, vi=-1e30f;
    for(int t=0;t<64;t++){ v0 = fmaxf(v0, sred[t]); vi = fmaxf(vi, sred[64+t]); }
    sred[128] = 1.f/(v0*vi);
  }
  __syncthreads();
  {
    float sc = sred[128];
    int i = tid>>2, j16 = (tid&3)*16;
    #pragma unroll
    for(int jj=0;jj<16;jj++){
      int j = j16+jj;
      u16 bvv = f2bf(bf2f(Kb[j*NS2+i])*sc);
      Vb[i*NS2+j] = bvv;
      Vt[j*NS2+i] = bvv;
    }
  }
  __syncthreads();
  f32x4 r4[4];
  for(int it=0; it<6; it++){
    ns_mm2(Kb, NS2, Vt, NS2, wv, q, c, r4);
    #pragma unroll
    for(int tc=0;tc<4;tc++){
      int col = 16*tc + c, row0 = 16*wv + 4*q;
      ushort4 pk;
      pk.x = f2bf(r4[tc][0]); pk.y = f2bf(r4[tc][1]); pk.z = f2bf(r4[tc][2]); pk.w = f2bf(r4[tc][3]);
      KVb[(row0+0)*NS2+col] = pk.x; KVb[(row0+1)*NS2+col] = pk.y;
      KVb[(row0+2)*NS2+col] = pk.z; KVb[(row0+3)*NS2+col] = pk.w;
      *(ushort4*)&KVt[(size_t)col*NS2 + row0] = pk;
    }
    __syncthreads();
    ns_mm2(KVb, NS2, KVt, NS2, wv, q, c, r4);
    #pragma unroll
    for(int tc=0;tc<4;tc++){
      int col = 16*tc+c, row0 = 16*wv+4*q;
      ushort4 pk;
      #pragma unroll
      for(int r=0;r<4;r++){
        float kvv = bf2f(KVb[(row0+r)*NS2+col]);
        ((u16*)&pk)[r] = f2bf(7.f*kvv - r4[tc][r]);
      }
      *(ushort4*)&Tt[(size_t)col*TTS + row0] = pk;
    }
    __syncthreads();
    ns_mm2(KVb, NS2, Tt, TTS, wv, q, c, r4);
    __syncthreads();
    #pragma unroll
    for(int tc=0;tc<4;tc++){
      int col = 16*tc+c, row0 = 16*wv+4*q;
      ushort4 pk;
      #pragma unroll
      for(int r=0;r<4;r++){
        float kvv = bf2f(KVb[(row0+r)*NS2+col]);
        ((u16*)&pk)[r] = f2bf(15.f*kvv - r4[tc][r]);
      }
      *(ushort4*)&Tt[(size_t)col*TTS + row0] = pk;
    }
    __syncthreads();
    ns_mm2(Vb, NS2, Tt, TTS, wv, q, c, r4);
    __syncthreads();
    #pragma unroll
    for(int tc=0;tc<4;tc++){
      int col = 16*tc+c, row0 = 16*wv+4*q;
      float nv[4]; ushort4 pk;
      #pragma unroll
      for(int r=0;r<4;r++){
        float vv = bf2f(Vb[(row0+r)*NS2+col]);
        nv[r] = 0.25f*(13.f*vv - r4[tc][r]);
        u16 bb = f2bf(nv[r]);
        Vb[(row0+r)*NS2+col] = bb;
        ((u16*)&pk)[r] = bb;
      }
      *(ushort4*)&Vt[(size_t)col*NS2 + row0] = pk;
      if(it==5){
        *(float4*)&KinvT[(size_t)n*4096 + (size_t)col*64 + row0] = make_float4(nv[0],nv[1],nv[2],nv[3]);
      }
    }
    __syncthreads();
  }
}

// ---------------- Z1/Z3 landmark GEMM (pure — ns moved to k_pv grid) ------------------------
#define LGS 264   // A LDS row stride (u16): 528B, 16B aligned, bank-conflict-free
__global__ __launch_bounds__(256) void k_landgemm(const u16* __restrict__ Y, const float* __restrict__ qland,
                                                  const float* __restrict__ kland, float* __restrict__ Z1,
                                                  float* __restrict__ Z3){
  __shared__ __align__(16) u16 As[64*LGS];
  __shared__ __align__(16) u16 BsU[2*64*64];
  const int z = blockIdx.y;
  const int n = z>>1, which = z&1;
  const int b0 = blockIdx.x*64;
  const float* land = (which ? qland : kland) + (size_t)n*LND*EDIM;
  const int boff = which ? 256 : 0;
  float* out = (which ? Z3 : Z1) + (size_t)n*LND*HWN;
  const u16* Yb = Y + (size_t)n*M3*HWN + boff;
  const int tid = threadIdx.x, lane = tid&63;
  const int c = tid&15, qq = (tid>>4)&3, wv = tid>>6;
  {
    int r = tid>>2, c0 = (tid&3)*64;
    const float* lp = land + (size_t)r*EDIM + c0;
    u16* dp = &As[r*LGS + c0];
    #pragma unroll
    for(int j=0;j<64;j+=4){
      float4 v = *(const float4*)(lp+j);
      ushort4 o; o.x=f2bf(v.x); o.y=f2bf(v.y); o.z=f2bf(v.z); o.w=f2bf(v.w);
      *(ushort4*)(dp+j) = o;
    }
  }
  const int srow  = wv*8 + (lane>>3);            // 0..31
  const int dslot = lane&7;
  const int sgo   = (dslot ^ (lane>>3))*8;       // row&7 == lane>>3 here
  const int rdswz = (c&7);
  f32x4 acc[4];
  #pragma unroll
  for(int nt=0;nt<4;nt++){ acc[nt][0]=0.f; acc[nt][1]=0.f; acc[nt][2]=0.f; acc[nt][3]=0.f; }
  #pragma unroll
  for(int j=0;j<2;j++){
    int r = j*32 + srow;
    gl16(Yb + (size_t)(b0+r)*M3 + sgo, BsU + r*64 + dslot*8);
  }
  __syncthreads();
  for(int ph=0; ph<4; ph++){
    const int cur = ph&1;
    if(ph<3){
      #pragma unroll
      for(int j=0;j<2;j++){
        int r = j*32 + srow;
        gl16(Yb + (size_t)(b0+r)*M3 + (ph+1)*64 + sgo, BsU + (cur^1)*4096 + r*64 + dslot*8);
      }
    }
    #pragma unroll
    for(int kt=0;kt<2;kt++){
      short8 af = *(const short8*)&As[(16*wv + c)*LGS + ph*64 + kt*32 + qq*8];
      const int rslot = ((kt*4+qq)^rdswz)*8;
      #pragma unroll
      for(int nt=0;nt<4;nt++){
        short8 bff = *(const short8*)&BsU[cur*4096 + (nt*16+c)*64 + rslot];
        acc[nt] = __builtin_amdgcn_mfma_f32_16x16x32_bf16(af, bff, acc[nt], 0, 0, 0);
      }
    }
    __syncthreads();
  }
  const int m0 = 16*wv + 4*qq;
  #pragma unroll
  for(int nt=0;nt<4;nt++){
    int col = b0 + nt*16 + c;
    out[(size_t)(m0+0)*HWN + col] = acc[nt][0];
    out[(size_t)(m0+1)*HWN + col] = acc[nt][1];
    out[(size_t)(m0+2)*HWN + col] = acc[nt][2];
    out[(size_t)(m0+3)*HWN + col] = acc[nt][3];
  }
}

// ---------------- soft1 body: softmax of Z1 over contiguous 4096 ----------------
__device__ void soft1_body(int b, char* smem, float* __restrict__ Z1){
  const int n = b>>6, j = b&63, tid = threadIdx.x;
  float* redm = (float*)smem;
  float* reds = redm + 4;
  float* base = Z1 + ((size_t)n*LND + j)*HWN;
  float v[16];
  float m = -1e30f;
  #pragma unroll
  for(int r=0;r<16;r++){ v[r] = base[r*256 + tid]; m = fmaxf(m, v[r]); }
  #pragma unroll
  for(int o=32;o;o>>=1) m = fmaxf(m, __shfl_xor(m, o));
  const int wid = tid>>6;
  if((tid&63)==0) redm[wid] = m;
  __syncthreads();
  m = fmaxf(fmaxf(redm[0],redm[1]), fmaxf(redm[2],redm[3]));
  float s = 0.f;
  #pragma unroll
  for(int r=0;r<16;r++){ v[r] = __expf(v[r]-m); s += v[r]; }
  #pragma unroll
  for(int o=32;o;o>>=1) s += __shfl_xor(s, o);
  if((tid&63)==0) reds[wid] = s;
  __syncthreads();
  s = reds[0]+reds[1]+reds[2]+reds[3];
  float inv = 1.f/s;
  #pragma unroll
  for(int r=0;r<16;r++) base[r*256 + tid] = v[r]*inv;
}

// ---------------- fused soft3 + PV GEMM + soft1 + NS (ns = blocks 0-7, dispatched first) ----
// LDS union 54272 B <= 163840/3 -> still 3 blocks/CU. ns_body is the verified round-8
// 4-wave version; it overlaps here with 1024 pv/soft1 blocks instead of serializing
// behind landgemm's GEMM (round-8 PMC: ns tail = ~47us at 0.4% occupancy there).
__global__ __launch_bounds__(256) void k_pv(const float* __restrict__ Z3, const u16* __restrict__ Y,
                                            float* __restrict__ part, float* __restrict__ Z1,
                                            const float* __restrict__ qland, const float* __restrict__ kland,
                                            float* __restrict__ KinvT){
  __shared__ __align__(16) char smem[54272];
  const int bi = blockIdx.x;
  if(bi < 8){ ns_body(bi, smem, qland, kland, KinvT); return; }
  if(bi >= 520){ soft1_body(bi-520, smem, Z1); return; }
  float* Sf   = (float*)smem;              // [64][132] logits -> exp   (0..33792)
  float* sinv = (float*)(smem + 33792);    // [128] 1/sum               (33792..34304)
  u16*   Asb  = (u16*)(smem + 34304);      // [2][64][64] P bf16, XOR-swizzled (..50688)
  u16*   Vt   = (u16*)smem;                // [128 e][64 j] per phase — overlays Sf (dead)
  const int idx = bi - 8;
  const int kc = idx&31, n = (idx>>5)&7, eh = idx>>8;
  const int jb = kc*128, eb = eh*128;
  const int tid = threadIdx.x, lane = tid&63;
  const int c = tid&15, qq = (tid>>4)&3, wv = tid>>6;
  const u16* Yb = Y + (size_t)n*M3*HWN;       // raw view: V[j][e] = flat[j*768 + 512 + e]
  const float* z3b = Z3 + (size_t)n*LND*HWN;
  // ---- soft3: stage logits ----
  {
    int ibase = (tid>>5)*8, j4 = (tid&31)*4;
    #pragma unroll
    for(int r=0;r<8;r++){
      int i = ibase + r;
      *(float4*)&Sf[i*132 + j4] = *(const float4*)&z3b[(size_t)i*HWN + jb + j4];
    }
  }
  __syncthreads();
  if(tid < 128){
    int j = tid;
    float m = -1e30f;
    for(int i=0;i<64;i++) m = fmaxf(m, Sf[i*132 + j]);
    float s = 0.f;
    for(int i=0;i<64;i++){ float e = __expf(Sf[i*132 + j] - m); Sf[i*132 + j] = e; s += e; }
    sinv[j] = 1.f/s;
  }
  __syncthreads();
  // ---- write P bf16 straight into swizzled A buffers (both phases) ----
  {
    int i = tid>>2, j0q = (tid&3)*32;
    const int iswz = (i&7);
    #pragma unroll
    for(int t=0;t<32;t+=4){
      int jg = j0q + t;                 // 0..127
      int phb = jg>>6, jl = jg&63;
      ushort4 o;
      o.x = f2bf(Sf[i*132 + jg+0]*sinv[jg+0]);
      o.y = f2bf(Sf[i*132 + jg+1]*sinv[jg+1]);
      o.z = f2bf(Sf[i*132 + jg+2]*sinv[jg+2]);
      o.w = f2bf(Sf[i*132 + jg+3]*sinv[jg+3]);
      *(ushort4*)&Asb[phb*4096 + i*64 + ((jl>>3)^iswz)*8 + (jl&7)] = o;
    }
  }
  __syncthreads();   // Sf dead from here; Vt may overlay it
  const int rdswz = (c&7);
  f32x4 acc[4][2];
  #pragma unroll
  for(int mt=0;mt<4;mt++)
    #pragma unroll
    for(int nt=0;nt<2;nt++){ acc[mt][nt][0]=0.f; acc[mt][nt][1]=0.f; acc[mt][nt][2]=0.f; acc[mt][nt][3]=0.f; }
  for(int ph=0; ph<2; ph++){
    #pragma unroll
    for(int rep=0; rep<4; rep++){
      int jl = (tid>>4) + 16*rep;                       // 0..63
      int ec = (tid&15)*8;                              // 0..120
      uint4 U = *(const uint4*)&Yb[(size_t)(jb+ph*64+jl)*M3 + 512 + eb + ec];
      const u16* uv = (const u16*)&U;
      #pragma unroll
      for(int k=0;k<8;k++){
        int e = ec+k;
        int slot = ((jl>>3) ^ (e&7) ^ ((e>>3)&7)) & 7;
        Vt[e*64 + slot*8 + (jl&7)] = uv[k];
      }
    }
    __syncthreads();
    #pragma unroll
    for(int kt=0;kt<2;kt++){
      const int rslotA = ((kt*4+qq)^rdswz)*8;
      short8 af[4];
      #pragma unroll
      for(int mt=0;mt<4;mt++) af[mt] = *(const short8*)&Asb[ph*4096 + (mt*16+c)*64 + rslotA];
      #pragma unroll
      for(int nt=0;nt<2;nt++){
        int e = wv*32 + nt*16 + c;
        int slotB = ((kt*4+qq) ^ (e&7) ^ ((e>>3)&7)) & 7;
        short8 bf_ = *(const short8*)&Vt[e*64 + slotB*8];
        #pragma unroll
        for(int mt=0;mt<4;mt++)
          acc[mt][nt] = __builtin_amdgcn_mfma_f32_16x16x32_bf16(af[mt], bf_, acc[mt][nt], 0, 0, 0);
      }
    }
    __syncthreads();
  }
  float* pb = part + ((size_t)n*32 + kc)*LND*EDIM + eb;
  #pragma unroll
  for(int mt=0;mt<4;mt++){
    int row0 = mt*16 + 4*qq;
    #pragma unroll
    for(int nt=0;nt<2;nt++){
      int e = wv*32 + nt*16 + c;
      pb[(size_t)(row0+0)*EDIM + e] = acc[mt][nt][0];
      pb[(size_t)(row0+1)*EDIM + e] = acc[mt][nt][1];
      pb[(size_t)(row0+2)*EDIM + e] = acc[mt][nt][2];
      pb[(size_t)(row0+3)*EDIM + e] = acc[mt][nt][3];
    }
  }
}

// ---------------- C2T[n][e][j] (bf16) = (Kinv @ sum_kc part)[j][e], fused fred+c2 ----------
__global__ __launch_bounds__(256) void k_c2(const float* __restrict__ KinvT, const float* __restrict__ part,
                                            u16* __restrict__ C2T){
  const int eb = blockIdx.x*64, n = blockIdx.y, tid = threadIdx.x;
  __shared__ float KT[64][68];
  __shared__ float Bs2[64][68];
  __shared__ u16 Ct[64*72];
  {
    int l = tid>>2, o16 = (tid&3)*16;
    const float* kp = KinvT + (size_t)n*4096 + l*64 + o16;
    #pragma unroll
    for(int t=0;t<16;t+=4) *(float4*)&KT[l][o16+t] = *(const float4*)(kp+t);
    // fused k_fred: B3[l][eb+o16..+16] = sum_kc part[n][kc][l][...]
    const float* pp = part + (size_t)n*32*16384 + (size_t)l*256 + eb + o16;
    float4 s0 = {0,0,0,0}, s1 = {0,0,0,0}, s2 = {0,0,0,0}, s3 = {0,0,0,0};
    for(int kc=0;kc<32;kc++){
      const float* b = pp + (size_t)kc*16384;
      float4 v0 = *(const float4*)(b);
      float4 v1 = *(const float4*)(b+4);
      float4 v2 = *(const float4*)(b+8);
      float4 v3 = *(const float4*)(b+12);
      s0.x+=v0.x; s0.y+=v0.y; s0.z+=v0.z; s0.w+=v0.w;
      s1.x+=v1.x; s1.y+=v1.y; s1.z+=v1.z; s1.w+=v1.w;
      s2.x+=v2.x; s2.y+=v2.y; s2.z+=v2.z; s2.w+=v2.w;
      s3.x+=v3.x; s3.y+=v3.y; s3.z+=v3.z; s3.w+=v3.w;
    }
    *(float4*)&Bs2[l][o16+0]  = s0;
    *(float4*)&Bs2[l][o16+4]  = s1;
    *(float4*)&Bs2[l][o16+8]  = s2;
    *(float4*)&Bs2[l][o16+12] = s3;
  }
  __syncthreads();
  const int j0 = (tid>>4)*4, u0 = (tid&15)*4;
  float acc[4][4] = {};
  #pragma unroll 8
  for(int l=0;l<64;l++){
    f32x4 a = *(f32x4*)&KT[l][j0];
    f32x4 b = *(f32x4*)&Bs2[l][u0];
    #pragma unroll
    for(int s=0;s<4;s++)
      #pragma unroll
      for(int u=0;u<4;u++) acc[s][u] += a[s]*b[u];
  }
  // transpose to bf16 [e][j] via LDS, then coalesced global write
  #pragma unroll
  for(int s=0;s<4;s++)
    #pragma unroll
    for(int u=0;u<4;u++)
      Ct[(u0+u)*72 + j0+s] = f2bf(acc[s][u]);
  __syncthreads();
  {
    int e = tid>>2, j16 = (tid&3)*16;
    u16* op = C2T + ((size_t)n*256 + eb + e)*64 + j16;
    #pragma unroll
    for(int t=0;t<16;t+=4)
      *(ushort4*)(op+t) = *(const ushort4*)&Ct[e*72 + j16 + t];
  }
}

// ---------------- out[i][e] = sum_j Z1[j][i]*C2[j][e] + v[i][e]; MFMA, OM bf16 --------------
__global__ __launch_bounds__(256) void k_out(const float* __restrict__ Z1, const u16* __restrict__ C2T,
                                             const u16* __restrict__ Y, u16* __restrict__ OM){
  __shared__ __align__(16) u16 Cs[256*64];    // [256 e][64 j], gl16-swizzled
  __shared__ __align__(16) u16 Zt[64*72];     // [64 i][72 j]
  const int ib = blockIdx.x*64, n = blockIdx.y;
  const int tid = threadIdx.x, lane = tid&63;
  const int c = tid&15, qq = (tid>>4)&3, wv = tid>>6;
  const int srow  = wv*8 + (lane>>3);
  const int dslot = lane&7;
  const int sgo   = (dslot ^ (lane>>3))*8;
  const int rdswz = (c&7);
  const u16* cb = C2T + (size_t)n*256*64;
  #pragma unroll
  for(int j=0;j<8;j++){
    int r = j*32 + srow;
    gl16(cb + (size_t)r*64 + sgo, &Cs[r*64 + dslot*8]);
  }
  {
    int j = tid>>2, i16 = (tid&3)*16;
    const float* zp = Z1 + ((size_t)n*LND + j)*HWN + ib + i16;
    #pragma unroll
    for(int t=0;t<16;t+=4){
      float4 v = *(const float4*)(zp+t);
      Zt[(i16+t+0)*72 + j] = f2bf(v.x);
      Zt[(i16+t+1)*72 + j] = f2bf(v.y);
      Zt[(i16+t+2)*72 + j] = f2bf(v.z);
      Zt[(i16+t+3)*72 + j] = f2bf(v.w);
    }
  }
  __syncthreads();
  f32x4 acc[4][4];
  #pragma unroll
  for(int mt=0;mt<4;mt++)
    #pragma unroll
    for(int nt=0;nt<4;nt++){ acc[mt][nt][0]=0.f; acc[mt][nt][1]=0.f; acc[mt][nt][2]=0.f; acc[mt][nt][3]=0.f; }
  #pragma unroll
  for(int kt=0;kt<2;kt++){
    const int rslot = ((kt*4+qq)^rdswz)*8;
    short8 af[4], bf_[4];
    #pragma unroll
    for(int mt=0;mt<4;mt++) af[mt] = *(const short8*)&Cs[(wv*64+mt*16+c)*64 + rslot];
    #pragma unroll
    for(int nt=0;nt<4;nt++) bf_[nt] = *(const short8*)&Zt[(nt*16+c)*72 + kt*32 + qq*8];
    #pragma unroll
    for(int mt=0;mt<4;mt++)
      #pragma unroll
      for(int nt=0;nt<4;nt++)
        acc[mt][nt] = __builtin_amdgcn_mfma_f32_16x16x32_bf16(af[mt], bf_[nt], acc[mt][nt], 0, 0, 0);
  }
  // epilogue: e = wv*64 + mt*16 + 4*qq (+r), i = ib + nt*16 + c ; ushort4 V-add + store
  const u16* Yb = Y + (size_t)n*M3*HWN;
  u16* ob = OM + (size_t)n*HWN*EDIM;
  #pragma unroll
  for(int mt=0;mt<4;mt++){
    int e = wv*64 + mt*16 + 4*qq;
    #pragma unroll
    for(int nt=0;nt<4;nt++){
      int i = ib + nt*16 + c;
      ushort4 V4 = *(const ushort4*)(Yb + (size_t)i*M3 + 512 + e);
      ushort4 o;
      o.x = f2bf(acc[mt][nt][0] + bf2f(V4.x));
      o.y = f2bf(acc[mt][nt][1] + bf2f(V4.y));
      o.z = f2bf(acc[mt][nt][2] + bf2f(V4.z));
      o.w = f2bf(acc[mt][nt][3] + bf2f(V4.w));
      *(ushort4*)(ob + (size_t)i*EDIM + e) = o;
    }
  }
}

// ---------------- proj GEMM 128x128xK256; B read directly from OM raw [e'][p'] view ---------
__global__ __launch_bounds__(256) void k_proj(const u16* __restrict__ Wb, const u16* __restrict__ OM,
                                              const float* __restrict__ bias, float* __restrict__ out){
  __shared__ __align__(16) u16 As[128*64];
  __shared__ __align__(16) u16 Bt[128*64];    // [128 p][64 e'] slot-XOR layout
  const int bi = blockIdx.x;
  const int n = bi&7, rem = bi>>3;
  const int ch0 = (rem&1)*128, p0 = (rem>>1)*128;
  const int tid = threadIdx.x, lane = tid&63;
  const int c = tid&15, qq = (tid>>4)&3, w4 = tid>>6;
  const int wr0 = (w4&1)*64, wc0 = (w4>>1)*64;
  const u16* omb = OM + (size_t)n*HWN*EDIM;   // flat, viewed [256 e'][4096 p']
  const u16* wb = Wb + (size_t)ch0*EDIM;
  f32x4 acc[4][4];
  #pragma unroll
  for(int mt=0;mt<4;mt++)
    #pragma unroll
    for(int nt=0;nt<4;nt++){ acc[mt][nt][0]=0.f; acc[mt][nt][1]=0.f; acc[mt][nt][2]=0.f; acc[mt][nt][3]=0.f; }
  const int srow  = w4*8 + (lane>>3);
  const int dslot = lane&7;
  const int sgo   = (dslot ^ (lane>>3))*8;
  const int rdswz = (c&7);
  for(int ph=0; ph<4; ph++){
    #pragma unroll
    for(int j=0;j<4;j++){
      int r = j*32 + srow;
      gl16(wb + (size_t)r*EDIM + ph*64 + sgo, &As[r*64 + dslot*8]);
    }
    #pragma unroll
    for(int rep=0; rep<4; rep++){
      int ee = (tid>>4) + 16*rep;                       // 0..63 (e' within phase)
      int pc = (tid&15)*8;                              // 0..120
      uint4 U = *(const uint4*)&omb[(size_t)(ph*64+ee)*HWN + p0 + pc];
      const u16* uv = (const u16*)&U;
      #pragma unroll
      for(int k=0;k<8;k++){
        int p = pc+k;
        int slot = ((ee>>3) ^ (p&7) ^ ((p>>3)&7)) & 7;
        Bt[p*64 + slot*8 + (ee&7)] = uv[k];
      }
    }
    __syncthreads();
    #pragma unroll
    for(int kt=0;kt<2;kt++){
      const int rslot = ((kt*4+qq)^rdswz)*8;
      short8 af[4], bff[4];
      #pragma unroll
      for(int mt=0;mt<4;mt++) af[mt] = *(const short8*)&As[(wr0+mt*16+c)*64 + rslot];
      #pragma unroll
      for(int nt=0;nt<4;nt++){
        int p = wc0 + nt*16 + c;
        int slotB = ((kt*4+qq) ^ (p&7) ^ ((p>>3)&7)) & 7;
        bff[nt] = *(const short8*)&Bt[p*64 + slotB*8];
      }
      #pragma unroll
      for(int mt=0;mt<4;mt++)
        #pragma unroll
        for(int nt=0;nt<4;nt++)
          acc[mt][nt] = __builtin_amdgcn_mfma_f32_16x16x32_bf16(af[mt], bff[nt], acc[mt][nt], 0, 0, 0);
    }
    __syncthreads();
  }
  float* ob = out + (size_t)n*EDIM*HWN;
  #pragma unroll
  for(int mt=0;mt<4;mt++){
    int chb = ch0 + wr0 + mt*16 + 4*qq;
    float b0 = bias[chb], b1 = bias[chb+1], b2 = bias[chb+2], b3 = bias[chb+3];
    #pragma unroll
    for(int nt=0;nt<4;nt++){
      int p = p0 + wc0 + nt*16 + c;
      float* yp = ob + (size_t)chb*HWN + p;
      yp[0]             = acc[mt][nt][0]+b0;
      yp[HWN]           = acc[mt][nt][1]+b1;
      yp[2*(size_t)HWN] = acc[mt][nt][2]+b2;
      yp[3*(size_t)HWN] = acc[mt][nt][3]+b3;
    }
  }
}

extern "C" void kernel_launch(void* const* d_in, const int* in_sizes, int n_in,
                              void* d_out, int out_size, void* d_ws, size_t ws_size,
                              hipStream_t stream){
  (void)out_size; (void)ws_size;
  const float* x     = (const float*)d_in[0];
  const float* w_qkv = (const float*)d_in[1];
  const float* b_qkv = (const float*)d_in[2];
  const float* w_out = (const float*)d_in[3];
  const float* b_out = (const float*)d_in[4];
  for(int i=0;i<n_in;i++){
    switch(in_sizes[i]){
      case 8388608: x     = (const float*)d_in[i]; break;
      case 196608:  w_qkv = (const float*)d_in[i]; break;
      case 768:     b_qkv = (const float*)d_in[i]; break;
      case 65536:   w_out = (const float*)d_in[i]; break;
      case 256:     b_out = (const float*)d_in[i]; break;
      default: break;
    }
  }
  float* out = (float*)d_out;
  char* ws = (char*)d_ws;

  u16*   Y     = (u16*)(ws + 0);              // 50,331,648 B  bf16 [8][768*4096]
  float* qland = (float*)(ws + 50331648);
  float* kland = (float*)(ws + 50855936);
  float* Z1    = (float*)(ws + 51380224);
  float* Z3    = (float*)(ws + 59768832);
  float* KinvT = (float*)(ws + 68157440);
  float* part  = (float*)(ws + 68288512);     // 16 MB region (was Xt -> part)
  u16*   Xt    = (u16*)(ws + 68288512);
  u16*   C2T   = (u16*)(ws + 85065728);       // bf16 [8][256 e][64 j] = 256 KB
  u16*   OM    = (u16*)(ws + 86114304);       // 16 MB bf16
  // Wqb overlaps Z3 (Z3 written by k_landgemm AFTER k_qkv consumes Wqb — stream-ordered safe)
  u16*   Wqb   = (u16*)(ws + 59768832);       // 393,216 B bf16 [768][256]
  u16*   Wob   = (u16*)(ws + 102891520);      // 131,072 B bf16 [256][256] (persists to k_proj)

  k_prep    <<<dim3(2056),   256, 0, stream>>>(x, Xt, w_qkv, w_out, Wqb, Wob);
  k_qkv     <<<dim3(1536),   256, 0, stream>>>(Wqb, Xt, b_qkv, Y);
  k_land    <<<dim3(64,8),   256, 0, stream>>>(Y, qland, kland);
  k_landgemm<<<dim3(64,16),  256, 0, stream>>>(Y, qland, kland, Z1, Z3);
  k_pv      <<<dim3(1032),   256, 0, stream>>>(Z3, Y, part, Z1, qland, kland, KinvT);
  k_c2      <<<dim3(4,8),    256, 0, stream>>>(KinvT, part, C2T);
  k_out     <<<dim3(64,8),   256, 0, stream>>>(Z1, C2T, Y, OM);
  k_proj    <<<dim3(512),    256, 0, stream>>>(Wob, OM, b_out, out);
}

// Round 11
// 195.335 us; speedup vs baseline: 1.1836x; 1.0474x over previous
//
#include <hip/hip_runtime.h>
#include <hip/hip_bf16.h>

typedef unsigned short u16;
typedef __attribute__((ext_vector_type(4))) float f32x4;
typedef __attribute__((ext_vector_type(8))) short short8;

#define NB   8
#define CIN  256
#define EDIM 256
#define M3   768
#define HWN  4096
#define LND  64
#define NS2  72    // NS LDS row stride (bf16 elems): 144B, 16B aligned

__device__ __forceinline__ float bf2f(u16 u){ return __uint_as_float(((unsigned)u)<<16); }
__device__ __forceinline__ u16 f2bf(float f){ __hip_bfloat16 h = __float2bfloat16(f); return *reinterpret_cast<u16*>(&h); }
__device__ __forceinline__ void bf2x2(unsigned u, float &lo, float &hi){
  lo = __uint_as_float(u<<16);
  hi = __uint_as_float(u & 0xffff0000u);
}

typedef __attribute__((address_space(1))) unsigned as1_uint;
typedef __attribute__((address_space(3))) unsigned as3_uint;
// async global->LDS, 16B per lane; dest must be wave-uniform base + lane*16
__device__ __forceinline__ void gl16(const void* g, void* l){
  __builtin_amdgcn_global_load_lds((const as1_uint*)g, (as3_uint*)l, 16, 0, 0);
}

// ---------------- prep: Xt[n][p][c] (bf16) = transpose of X[n][c][p] (fp32) ----------------
__global__ __launch_bounds__(256) void k_prep(const float* __restrict__ x, u16* __restrict__ Xt,
                                              const float* __restrict__ wq, const float* __restrict__ wo,
                                              u16* __restrict__ Wqb, u16* __restrict__ Wob){
  const int bi = blockIdx.x;
  const int tid = threadIdx.x;
  if(bi >= 2048){
    int ti = (bi-2048)*256 + tid;          // 0..2047
    const float* src; u16* dst;
    if(ti < 1536){ src = wq + (size_t)ti*128;        dst = Wqb + (size_t)ti*128; }
    else         { src = wo + (size_t)(ti-1536)*128; dst = Wob + (size_t)(ti-1536)*128; }
    #pragma unroll
    for(int t=0;t<128;t+=8){
      float4 v0 = *(const float4*)(src+t);
      float4 v1 = *(const float4*)(src+t+4);
      ushort4 o0, o1;
      o0.x=f2bf(v0.x); o0.y=f2bf(v0.y); o0.z=f2bf(v0.z); o0.w=f2bf(v0.w);
      o1.x=f2bf(v1.x); o1.y=f2bf(v1.y); o1.z=f2bf(v1.z); o1.w=f2bf(v1.w);
      *(ushort4*)(dst+t)   = o0;
      *(ushort4*)(dst+t+4) = o1;
    }
    return;
  }
  __shared__ float Ts[64*65];
  const int n = bi>>8, rem = bi&255, ct = rem>>6, pt = rem&63;
  const int c0 = ct*64, p0 = pt*64;
  {
    int cc = tid>>2, pj = (tid&3)*16;
    const float* xp = x + (size_t)n*CIN*HWN + (size_t)(c0+cc)*HWN + p0 + pj;
    #pragma unroll
    for(int j=0;j<16;j++) Ts[cc*65 + pj + j] = xp[j];
  }
  __syncthreads();
  {
    int pp = tid>>2, ej = (tid&3)*16;
    u16* op = Xt + ((size_t)n*HWN + p0 + pp)*CIN + c0 + ej;
    ushort4 o[4];
    #pragma unroll
    for(int j=0;j<16;j++) ((u16*)o)[j] = f2bf(Ts[(ej+j)*65 + pp]);
    *(ushort4*)(op+0)  = o[0];
    *(ushort4*)(op+4)  = o[1];
    *(ushort4*)(op+8)  = o[2];
    *(ushort4*)(op+12) = o[3];
  }
}

// ---------------- QKV GEMM 128x128xK256 bf16 MFMA, global_load_lds + XOR swizzle ------------
__global__ __launch_bounds__(256) void k_qkv(const u16* __restrict__ Wb, const u16* __restrict__ Xt,
                                             const float* __restrict__ bias, u16* __restrict__ Y){
  __shared__ __align__(16) u16 As[128*64];
  __shared__ __align__(16) u16 Bs[128*64];
  const int bi = blockIdx.x;
  const int n = bi&7, rem = bi>>3;
  const int ch0 = (rem%6)*128, p0 = (rem/6)*128;
  const int tid = threadIdx.x, lane = tid&63;
  const int c = tid&15, qq = (tid>>4)&3, w4 = tid>>6;
  const int wr0 = (w4&1)*64, wc0 = (w4>>1)*64;
  const u16* xb = Xt + ((size_t)n*HWN + p0)*CIN;
  const u16* wb = Wb + (size_t)ch0*CIN;
  f32x4 acc[4][4];
  #pragma unroll
  for(int mt=0;mt<4;mt++)
    #pragma unroll
    for(int nt=0;nt<4;nt++){ acc[mt][nt][0]=0.f; acc[mt][nt][1]=0.f; acc[mt][nt][2]=0.f; acc[mt][nt][3]=0.f; }
  const int srow  = w4*8 + (lane>>3);
  const int dslot = lane&7;
  const int sgo   = (dslot ^ (lane>>3))*8;       // swizzled source u16 offset within row-chunk
  const int rdswz = (c&7);                        // read-side row&7
  for(int ph=0; ph<4; ph++){
    #pragma unroll
    for(int j=0;j<4;j++){
      int r = j*32 + srow;
      gl16(wb + (size_t)r*CIN + ph*64 + sgo, &As[r*64 + dslot*8]);
    }
    #pragma unroll
    for(int j=0;j<4;j++){
      int r = j*32 + srow;
      gl16(xb + (size_t)r*CIN + ph*64 + sgo, &Bs[r*64 + dslot*8]);
    }
    __syncthreads();
    #pragma unroll
    for(int kt=0;kt<2;kt++){
      short8 af[4], bff[4];
      const int rslot = ((kt*4+qq)^rdswz)*8;
      #pragma unroll
      for(int mt=0;mt<4;mt++) af[mt]  = *(const short8*)&As[(wr0+mt*16+c)*64 + rslot];
      #pragma unroll
      for(int nt=0;nt<4;nt++) bff[nt] = *(const short8*)&Bs[(wc0+nt*16+c)*64 + rslot];
      #pragma unroll
      for(int mt=0;mt<4;mt++)
        #pragma unroll
        for(int nt=0;nt<4;nt++)
          acc[mt][nt] = __builtin_amdgcn_mfma_f32_16x16x32_bf16(af[mt], bff[nt], acc[mt][nt], 0, 0, 0);
    }
    __syncthreads();
  }
  u16* Yb = Y + (size_t)n*M3*HWN;
  #pragma unroll
  for(int mt=0;mt<4;mt++){
    int chb = ch0 + wr0 + mt*16 + 4*qq;
    float b0 = bias[chb], b1 = bias[chb+1], b2 = bias[chb+2], b3 = bias[chb+3];
    #pragma unroll
    for(int nt=0;nt<4;nt++){
      int p = p0 + wc0 + nt*16 + c;
      u16* yp = Yb + (size_t)chb*HWN + p;
      yp[0]             = f2bf(acc[mt][nt][0]+b0);
      yp[HWN]           = f2bf(acc[mt][nt][1]+b1);
      yp[2*(size_t)HWN] = f2bf(acc[mt][nt][2]+b2);
      yp[3*(size_t)HWN] = f2bf(acc[mt][nt][3]+b3);
    }
  }
}

// ---------------- landmarks ----------------
__global__ void k_land(const u16* __restrict__ Y, float* __restrict__ qland, float* __restrict__ kland){
  const int l = blockIdx.x, n = blockIdx.y, e = threadIdx.x;
  const u16* base = Y + (size_t)n*M3*HWN;
  float qs=0.f, ks=0.f;
  #pragma unroll 8
  for(int m=0;m<64;m++){
    size_t off = (size_t)(l*64+m)*M3;
    qs += bf2f(base[off+e]);
    ks += bf2f(base[off+256+e]);
  }
  qland[((size_t)n*LND+l)*EDIM+e] = qs*(1.f/4096.f);
  kland[((size_t)n*LND+l)*EDIM+e] = ks*(1.f/4096.f);
}

// ---------------- NS 64x64 matmul via bf16 MFMA (per-operand LDS row stride) ----------------
__device__ __forceinline__ void ns_mm2(const u16* L, int sL, const u16* Rt, int sR,
                                       int wv, int q, int c, f32x4 r4[4]){
  short8 a0 = *(const short8*)(L + (size_t)(16*wv + c)*sL + 8*q);
  short8 a1 = *(const short8*)(L + (size_t)(16*wv + c)*sL + 32 + 8*q);
  #pragma unroll
  for(int tc=0;tc<4;tc++){
    f32x4 acc = {0.f,0.f,0.f,0.f};
    short8 b0 = *(const short8*)(Rt + (size_t)(16*tc + c)*sR + 8*q);
    short8 b1 = *(const short8*)(Rt + (size_t)(16*tc + c)*sR + 32 + 8*q);
    acc = __builtin_amdgcn_mfma_f32_16x16x32_bf16(a0, b0, acc, 0, 0, 0);
    acc = __builtin_amdgcn_mfma_f32_16x16x32_bf16(a1, b1, acc, 0, 0, 0);
    r4[tc] = acc;
  }
}

// ---- one rotated NS iteration: 4 barriers (M3 writes KVt — validated rotation, round 9) ----
// Hazard notes: A-operand reads (rows 16wv+c) and output-row writes (16wv+4q+r) are
// own-wave; only B-operand reads span waves, each covered by the preceding barrier.
#define TTS 64
__device__ __forceinline__ void ns_iter(u16* Kb, u16* Vb, u16* Vt, u16* KVb, u16* KVt, u16* Tt,
                                        int wv, int q, int c, bool last, int n,
                                        float* __restrict__ KinvT){
  f32x4 r4[4];
  // M1: KV = K @ V (B^T = Vt) -> KVb (own rows) + KVt (transpose)
  ns_mm2(Kb, NS2, Vt, NS2, wv, q, c, r4);
  #pragma unroll
  for(int tc=0;tc<4;tc++){
    int col = 16*tc + c, row0 = 16*wv + 4*q;
    ushort4 pk;
    pk.x = f2bf(r4[tc][0]); pk.y = f2bf(r4[tc][1]); pk.z = f2bf(r4[tc][2]); pk.w = f2bf(r4[tc][3]);
    KVb[(row0+0)*NS2+col] = pk.x; KVb[(row0+1)*NS2+col] = pk.y;
    KVb[(row0+2)*NS2+col] = pk.z; KVb[(row0+3)*NS2+col] = pk.w;
    *(ushort4*)&KVt[(size_t)col*NS2 + row0] = pk;
  }
  __syncthreads();
  // M2: r = KV @ KV ; Tt = (7KV - r)^T
  ns_mm2(KVb, NS2, KVt, NS2, wv, q, c, r4);
  #pragma unroll
  for(int tc=0;tc<4;tc++){
    int col = 16*tc+c, row0 = 16*wv+4*q;
    ushort4 pk;
    #pragma unroll
    for(int r=0;r<4;r++){
      float kvv = bf2f(KVb[(row0+r)*NS2+col]);
      ((u16*)&pk)[r] = f2bf(7.f*kvv - r4[tc][r]);
    }
    *(ushort4*)&Tt[(size_t)col*TTS + row0] = pk;
  }
  __syncthreads();
  // M3: r = KV @ T ; KVt = (15KV - r)^T   (KVt dead after M2 — no WAR barrier needed)
  ns_mm2(KVb, NS2, Tt, TTS, wv, q, c, r4);
  #pragma unroll
  for(int tc=0;tc<4;tc++){
    int col = 16*tc+c, row0 = 16*wv+4*q;
    ushort4 pk;
    #pragma unroll
    for(int r=0;r<4;r++){
      float kvv = bf2f(KVb[(row0+r)*NS2+col]);
      ((u16*)&pk)[r] = f2bf(15.f*kvv - r4[tc][r]);
    }
    *(ushort4*)&KVt[(size_t)col*NS2 + row0] = pk;
  }
  __syncthreads();
  // M4: r = V @ T2 (B^T = KVt) ; newV = 0.25(13V - r) -> Vb (own rows), Vt (transpose)
  ns_mm2(Vb, NS2, KVt, NS2, wv, q, c, r4);
  #pragma unroll
  for(int tc=0;tc<4;tc++){
    int col = 16*tc+c, row0 = 16*wv+4*q;
    float nv[4]; ushort4 pk;
    #pragma unroll
    for(int r=0;r<4;r++){
      float vv = bf2f(Vb[(row0+r)*NS2+col]);
      nv[r] = 0.25f*(13.f*vv - r4[tc][r]);
      u16 bb = f2bf(nv[r]);
      Vb[(row0+r)*NS2+col] = bb;
      ((u16*)&pk)[r] = bb;
    }
    *(ushort4*)&Vt[(size_t)col*NS2 + row0] = pk;
    if(last){
      *(float4*)&KinvT[(size_t)n*4096 + (size_t)col*64 + row0] = make_float4(nv[0],nv[1],nv[2],nv[3]);
    }
  }
  __syncthreads();
}

// ---------------- NS stage A: k2 + softmax + V0 + iters 0-2; store K,V (bf16) to NSst -------
__device__ void ns_body_A(int n, char* smem, const float* __restrict__ qland,
                          const float* __restrict__ kland, u16* __restrict__ NSst){
  u16* Kb  = (u16*)(smem + 0);
  u16* Vb  = (u16*)(smem + 9216);
  u16* Vt  = (u16*)(smem + 18432);
  u16* KVb = (u16*)(smem + 27648);
  u16* KVt = (u16*)(smem + 36864);
  u16* Tt  = (u16*)(smem + 46080);
  float* sS   = (float*)(smem + 27648);    // 64x66 f32, aliases KVb/KVt
  float* sred = (float*)(smem + 44544);
  const int tid = threadIdx.x;
  const int wv = tid>>6, q = (tid>>4)&3, c = tid&15;
  const float* qb = qland + (size_t)n*LND*EDIM;
  const float* kb = kland + (size_t)n*LND*EDIM;
  f32x4 acc[4];
  #pragma unroll
  for(int t=0;t<4;t++){ acc[t][0]=0.f; acc[t][1]=0.f; acc[t][2]=0.f; acc[t][3]=0.f; }
  for(int e0=0;e0<EDIM;e0+=64){
    __syncthreads();
    {
      int row = tid>>2, c0 = (tid&3)*16;
      const float* qp = qb + (size_t)row*EDIM + e0 + c0;
      const float* kp = kb + (size_t)row*EDIM + e0 + c0;
      u16* qd = &KVb[row*NS2 + c0];
      u16* kd = &KVt[row*NS2 + c0];
      #pragma unroll
      for(int j=0;j<16;j+=4){
        float4 qv = *(const float4*)(qp+j);
        float4 kv = *(const float4*)(kp+j);
        ushort4 qo, ko;
        qo.x=f2bf(qv.x); qo.y=f2bf(qv.y); qo.z=f2bf(qv.z); qo.w=f2bf(qv.w);
        ko.x=f2bf(kv.x); ko.y=f2bf(kv.y); ko.z=f2bf(kv.z); ko.w=f2bf(kv.w);
        *(ushort4*)(qd+j) = qo;
        *(ushort4*)(kd+j) = ko;
      }
    }
    __syncthreads();
    {
      short8 a0 = *(const short8*)&KVb[(16*wv+c)*NS2 + 8*q];
      short8 a1 = *(const short8*)&KVb[(16*wv+c)*NS2 + 32 + 8*q];
      #pragma unroll
      for(int tc=0;tc<4;tc++){
        short8 b0 = *(const short8*)&KVt[(16*tc+c)*NS2 + 8*q];
        short8 b1 = *(const short8*)&KVt[(16*tc+c)*NS2 + 32 + 8*q];
        acc[tc] = __builtin_amdgcn_mfma_f32_16x16x32_bf16(a0, b0, acc[tc], 0, 0, 0);
        acc[tc] = __builtin_amdgcn_mfma_f32_16x16x32_bf16(a1, b1, acc[tc], 0, 0, 0);
      }
    }
  }
  __syncthreads();
  #pragma unroll
  for(int tc=0;tc<4;tc++){
    int col = 16*tc + c, row0 = 16*wv + 4*q;
    sS[(row0+0)*66+col] = acc[tc][0];
    sS[(row0+1)*66+col] = acc[tc][1];
    sS[(row0+2)*66+col] = acc[tc][2];
    sS[(row0+3)*66+col] = acc[tc][3];
  }
  __syncthreads();
  if(tid < 64){
    int j = tid;
    float m = -1e30f;
    for(int i=0;i<64;i++) m = fmaxf(m, sS[i*66+j]);
    float ssum = 0.f;
    for(int i=0;i<64;i++) ssum += __expf(sS[i*66+j]-m);
    float inv = 1.f/ssum, cs = 0.f;
    for(int i=0;i<64;i++){
      float kv = __expf(sS[i*66+j]-m)*inv;
      cs += fabsf(kv);
      Kb[i*NS2+j] = f2bf(kv);
    }
    sred[j] = cs;
  }
  __syncthreads();
  if(tid < 64){
    int i = tid; float rs = 0.f;
    for(int j=0;j<64;j++) rs += fabsf(bf2f(Kb[i*NS2+j]));
    sred[64+i] = rs;
  }
  __syncthreads();
  if(tid == 0){
    float v0=-1e30f, vi=-1e30f;
    for(int t=0;t<64;t++){ v0 = fmaxf(v0, sred[t]); vi = fmaxf(vi, sred[64+t]); }
    sred[128] = 1.f/(v0*vi);
  }
  __syncthreads();
  {
    float sc = sred[128];
    int i = tid>>2, j16 = (tid&3)*16;
    #pragma unroll
    for(int jj=0;jj<16;jj++){
      int j = j16+jj;
      u16 bvv = f2bf(bf2f(Kb[j*NS2+i])*sc);
      Vb[i*NS2+j] = bvv;
      Vt[j*NS2+i] = bvv;
    }
  }
  __syncthreads();
  for(int it=0; it<3; it++)
    ns_iter(Kb, Vb, Vt, KVb, KVt, Tt, wv, q, c, false, n, (float*)0);
  // store K,V (bf16) — after iter-2's end barrier all Vb rows are visible
  {
    int i = tid>>2, j16 = (tid&3)*16;
    u16* kd = NSst + (size_t)n*4096 + i*64 + j16;
    u16* vd = NSst + (size_t)(8+n)*4096 + i*64 + j16;
    #pragma unroll
    for(int t=0;t<16;t+=4){
      *(ushort4*)(kd+t) = *(const ushort4*)&Kb[i*NS2 + j16 + t];
      *(ushort4*)(vd+t) = *(const ushort4*)&Vb[i*NS2 + j16 + t];
    }
  }
}

// ---------------- NS stage B: reload K,V; rebuild Vt; iters 3-5; write KinvT ----------------
__device__ void ns_body_B(int n, char* smem, const u16* __restrict__ NSst, float* __restrict__ KinvT){
  u16* Kb  = (u16*)(smem + 0);
  u16* Vb  = (u16*)(smem + 9216);
  u16* Vt  = (u16*)(smem + 18432);
  u16* KVb = (u16*)(smem + 27648);
  u16* KVt = (u16*)(smem + 36864);
  u16* Tt  = (u16*)(smem + 46080);
  const int tid = threadIdx.x;
  const int wv = tid>>6, q = (tid>>4)&3, c = tid&15;
  {
    int i = tid>>2, j16 = (tid&3)*16;
    const u16* ks = NSst + (size_t)n*4096 + i*64 + j16;
    const u16* vs = NSst + (size_t)(8+n)*4096 + i*64 + j16;
    #pragma unroll
    for(int t=0;t<16;t+=4){
      ushort4 kk = *(const ushort4*)(ks+t);
      ushort4 vv = *(const ushort4*)(vs+t);
      *(ushort4*)&Kb[i*NS2 + j16 + t] = kk;
      *(ushort4*)&Vb[i*NS2 + j16 + t] = vv;
      Vt[(j16+t+0)*NS2 + i] = vv.x;
      Vt[(j16+t+1)*NS2 + i] = vv.y;
      Vt[(j16+t+2)*NS2 + i] = vv.z;
      Vt[(j16+t+3)*NS2 + i] = vv.w;
    }
  }
  __syncthreads();
  for(int it=3; it<6; it++)
    ns_iter(Kb, Vb, Vt, KVb, KVt, Tt, wv, q, c, it==5, n, KinvT);
}

// ---------------- Z1/Z3 landmark GEMM + fused NS stage A (blockIdx.x==64) -------------------
#define LGS 264   // A LDS row stride (u16): 528B, 16B aligned, bank-conflict-free
__global__ __launch_bounds__(256) void k_landgemm(const u16* __restrict__ Y, const float* __restrict__ qland,
                                                  const float* __restrict__ kland, float* __restrict__ Z1,
                                                  float* __restrict__ Z3, u16* __restrict__ NSst){
  __shared__ __align__(16) char usm[54272];
  const int z = blockIdx.y;
  if(blockIdx.x == 64){
    if((z&1)==0) ns_body_A(z>>1, usm, qland, kland, NSst);
    return;
  }
  u16* As = (u16*)usm;                 // [64][LGS]
  u16* BsU = (u16*)(usm + 33792);      // [2][64*64]
  const int n = z>>1, which = z&1;
  const int b0 = blockIdx.x*64;
  const float* land = (which ? qland : kland) + (size_t)n*LND*EDIM;
  const int boff = which ? 256 : 0;
  float* out = (which ? Z3 : Z1) + (size_t)n*LND*HWN;
  const u16* Yb = Y + (size_t)n*M3*HWN + boff;
  const int tid = threadIdx.x, lane = tid&63;
  const int c = tid&15, qq = (tid>>4)&3, wv = tid>>6;
  {
    int r = tid>>2, c0 = (tid&3)*64;
    const float* lp = land + (size_t)r*EDIM + c0;
    u16* dp = &As[r*LGS + c0];
    #pragma unroll
    for(int j=0;j<64;j+=4){
      float4 v = *(const float4*)(lp+j);
      ushort4 o; o.x=f2bf(v.x); o.y=f2bf(v.y); o.z=f2bf(v.z); o.w=f2bf(v.w);
      *(ushort4*)(dp+j) = o;
    }
  }
  const int srow  = wv*8 + (lane>>3);            // 0..31
  const int dslot = lane&7;
  const int sgo   = (dslot ^ (lane>>3))*8;       // row&7 == lane>>3 here
  const int rdswz = (c&7);
  f32x4 acc[4];
  #pragma unroll
  for(int nt=0;nt<4;nt++){ acc[nt][0]=0.f; acc[nt][1]=0.f; acc[nt][2]=0.f; acc[nt][3]=0.f; }
  #pragma unroll
  for(int j=0;j<2;j++){
    int r = j*32 + srow;
    gl16(Yb + (size_t)(b0+r)*M3 + sgo, BsU + r*64 + dslot*8);
  }
  __syncthreads();
  for(int ph=0; ph<4; ph++){
    const int cur = ph&1;
    if(ph<3){
      #pragma unroll
      for(int j=0;j<2;j++){
        int r = j*32 + srow;
        gl16(Yb + (size_t)(b0+r)*M3 + (ph+1)*64 + sgo, BsU + (cur^1)*4096 + r*64 + dslot*8);
      }
    }
    #pragma unroll
    for(int kt=0;kt<2;kt++){
      short8 af = *(const short8*)&As[(16*wv + c)*LGS + ph*64 + kt*32 + qq*8];
      const int rslot = ((kt*4+qq)^rdswz)*8;
      #pragma unroll
      for(int nt=0;nt<4;nt++){
        short8 bff = *(const short8*)&BsU[cur*4096 + (nt*16+c)*64 + rslot];
        acc[nt] = __builtin_amdgcn_mfma_f32_16x16x32_bf16(af, bff, acc[nt], 0, 0, 0);
      }
    }
    __syncthreads();
  }
  const int m0 = 16*wv + 4*qq;
  #pragma unroll
  for(int nt=0;nt<4;nt++){
    int col = b0 + nt*16 + c;
    out[(size_t)(m0+0)*HWN + col] = acc[nt][0];
    out[(size_t)(m0+1)*HWN + col] = acc[nt][1];
    out[(size_t)(m0+2)*HWN + col] = acc[nt][2];
    out[(size_t)(m0+3)*HWN + col] = acc[nt][3];
  }
}

// ---------------- soft1 body: softmax of Z1 over contiguous 4096 ----------------
__device__ void soft1_body(int b, char* smem, float* __restrict__ Z1){
  const int n = b>>6, j = b&63, tid = threadIdx.x;
  float* redm = (float*)smem;
  float* reds = redm + 4;
  float* base = Z1 + ((size_t)n*LND + j)*HWN;
  float v[16];
  float m = -1e30f;
  #pragma unroll
  for(int r=0;r<16;r++){ v[r] = base[r*256 + tid]; m = fmaxf(m, v[r]); }
  #pragma unroll
  for(int o=32;o;o>>=1) m = fmaxf(m, __shfl_xor(m, o));
  const int wid = tid>>6;
  if((tid&63)==0) redm[wid] = m;
  __syncthreads();
  m = fmaxf(fmaxf(redm[0],redm[1]), fmaxf(redm[2],redm[3]));
  float s = 0.f;
  #pragma unroll
  for(int r=0;r<16;r++){ v[r] = __expf(v[r]-m); s += v[r]; }
  #pragma unroll
  for(int o=32;o;o>>=1) s += __shfl_xor(s, o);
  if((tid&63)==0) reds[wid] = s;
  __syncthreads();
  s = reds[0]+reds[1]+reds[2]+reds[3];
  float inv = 1.f/s;
  #pragma unroll
  for(int r=0;r<16;r++) base[r*256 + tid] = v[r]*inv;
}

// ---------------- fused soft3 + PV GEMM + soft1 + NS stage B (blocks 0-7 first) -------------
__global__ __launch_bounds__(256) void k_pv(const float* __restrict__ Z3, const u16* __restrict__ Y,
                                            float* __restrict__ part, float* __restrict__ Z1,
                                            const u16* __restrict__ NSst, float* __restrict__ KinvT){
  __shared__ __align__(16) char smem[54272];
  const int bi = blockIdx.x;
  if(bi < 8){ ns_body_B(bi, smem, NSst, KinvT); return; }
  if(bi >= 520){ soft1_body(bi-520, smem, Z1); return; }
  float* Sf   = (float*)smem;              // [64][132] logits -> exp   (0..33792)
  float* sinv = (float*)(smem + 33792);    // [128] 1/sum               (33792..34304)
  u16*   Asb  = (u16*)(smem + 34304);      // [2][64][64] P bf16, XOR-swizzled (..50688)
  u16*   Vt   = (u16*)smem;                // [128 e][64 j] per phase — overlays Sf (dead)
  const int idx = bi - 8;
  const int kc = idx&31, n = (idx>>5)&7, eh = idx>>8;
  const int jb = kc*128, eb = eh*128;
  const int tid = threadIdx.x, lane = tid&63;
  const int c = tid&15, qq = (tid>>4)&3, wv = tid>>6;
  const u16* Yb = Y + (size_t)n*M3*HWN;       // raw view: V[j][e] = flat[j*768 + 512 + e]
  const float* z3b = Z3 + (size_t)n*LND*HWN;
  // ---- soft3: stage logits ----
  {
    int ibase = (tid>>5)*8, j4 = (tid&31)*4;
    #pragma unroll
    for(int r=0;r<8;r++){
      int i = ibase + r;
      *(float4*)&Sf[i*132 + j4] = *(const float4*)&z3b[(size_t)i*HWN + jb + j4];
    }
  }
  __syncthreads();
  if(tid < 128){
    int j = tid;
    float m = -1e30f;
    for(int i=0;i<64;i++) m = fmaxf(m, Sf[i*132 + j]);
    float s = 0.f;
    for(int i=0;i<64;i++){ float e = __expf(Sf[i*132 + j] - m); Sf[i*132 + j] = e; s += e; }
    sinv[j] = 1.f/s;
  }
  __syncthreads();
  // ---- write P bf16 straight into swizzled A buffers (both phases) ----
  {
    int i = tid>>2, j0q = (tid&3)*32;
    const int iswz = (i&7);
    #pragma unroll
    for(int t=0;t<32;t+=4){
      int jg = j0q + t;                 // 0..127
      int phb = jg>>6, jl = jg&63;
      ushort4 o;
      o.x = f2bf(Sf[i*132 + jg+0]*sinv[jg+0]);
      o.y = f2bf(Sf[i*132 + jg+1]*sinv[jg+1]);
      o.z = f2bf(Sf[i*132 + jg+2]*sinv[jg+2]);
      o.w = f2bf(Sf[i*132 + jg+3]*sinv[jg+3]);
      *(ushort4*)&Asb[phb*4096 + i*64 + ((jl>>3)^iswz)*8 + (jl&7)] = o;
    }
  }
  __syncthreads();   // Sf dead from here; Vt may overlay it
  const int rdswz = (c&7);
  f32x4 acc[4][2];
  #pragma unroll
  for(int mt=0;mt<4;mt++)
    #pragma unroll
    for(int nt=0;nt<2;nt++){ acc[mt][nt][0]=0.f; acc[mt][nt][1]=0.f; acc[mt][nt][2]=0.f; acc[mt][nt][3]=0.f; }
  for(int ph=0; ph<2; ph++){
    #pragma unroll
    for(int rep=0; rep<4; rep++){
      int jl = (tid>>4) + 16*rep;                       // 0..63
      int ec = (tid&15)*8;                              // 0..120
      uint4 U = *(const uint4*)&Yb[(size_t)(jb+ph*64+jl)*M3 + 512 + eb + ec];
      const u16* uv = (const u16*)&U;
      #pragma unroll
      for(int k=0;k<8;k++){
        int e = ec+k;
        int slot = ((jl>>3) ^ (e&7) ^ ((e>>3)&7)) & 7;
        Vt[e*64 + slot*8 + (jl&7)] = uv[k];
      }
    }
    __syncthreads();
    #pragma unroll
    for(int kt=0;kt<2;kt++){
      const int rslotA = ((kt*4+qq)^rdswz)*8;
      short8 af[4];
      #pragma unroll
      for(int mt=0;mt<4;mt++) af[mt] = *(const short8*)&Asb[ph*4096 + (mt*16+c)*64 + rslotA];
      #pragma unroll
      for(int nt=0;nt<2;nt++){
        int e = wv*32 + nt*16 + c;
        int slotB = ((kt*4+qq) ^ (e&7) ^ ((e>>3)&7)) & 7;
        short8 bf_ = *(const short8*)&Vt[e*64 + slotB*8];
        #pragma unroll
        for(int mt=0;mt<4;mt++)
          acc[mt][nt] = __builtin_amdgcn_mfma_f32_16x16x32_bf16(af[mt], bf_, acc[mt][nt], 0, 0, 0);
      }
    }
    __syncthreads();
  }
  float* pb = part + ((size_t)n*32 + kc)*LND*EDIM + eb;
  #pragma unroll
  for(int mt=0;mt<4;mt++){
    int row0 = mt*16 + 4*qq;
    #pragma unroll
    for(int nt=0;nt<2;nt++){
      int e = wv*32 + nt*16 + c;
      pb[(size_t)(row0+0)*EDIM + e] = acc[mt][nt][0];
      pb[(size_t)(row0+1)*EDIM + e] = acc[mt][nt][1];
      pb[(size_t)(row0+2)*EDIM + e] = acc[mt][nt][2];
      pb[(size_t)(row0+3)*EDIM + e] = acc[mt][nt][3];
    }
  }
}

// ---------------- C2T[n][e][j] (bf16) = (Kinv @ sum_kc part)[j][e], fused fred+c2 ----------
__global__ __launch_bounds__(256) void k_c2(const float* __restrict__ KinvT, const float* __restrict__ part,
                                            u16* __restrict__ C2T){
  const int eb = blockIdx.x*64, n = blockIdx.y, tid = threadIdx.x;
  __shared__ float KT[64][68];
  __shared__ float Bs2[64][68];
  __shared__ u16 Ct[64*72];
  {
    int l = tid>>2, o16 = (tid&3)*16;
    const float* kp = KinvT + (size_t)n*4096 + l*64 + o16;
    #pragma unroll
    for(int t=0;t<16;t+=4) *(float4*)&KT[l][o16+t] = *(const float4*)(kp+t);
    const float* pp = part + (size_t)n*32*16384 + (size_t)l*256 + eb + o16;
    float4 s0 = {0,0,0,0}, s1 = {0,0,0,0}, s2 = {0,0,0,0}, s3 = {0,0,0,0};
    for(int kc=0;kc<32;kc++){
      const float* b = pp + (size_t)kc*16384;
      float4 v0 = *(const float4*)(b);
      float4 v1 = *(const float4*)(b+4);
      float4 v2 = *(const float4*)(b+8);
      float4 v3 = *(const float4*)(b+12);
      s0.x+=v0.x; s0.y+=v0.y; s0.z+=v0.z; s0.w+=v0.w;
      s1.x+=v1.x; s1.y+=v1.y; s1.z+=v1.z; s1.w+=v1.w;
      s2.x+=v2.x; s2.y+=v2.y; s2.z+=v2.z; s2.w+=v2.w;
      s3.x+=v3.x; s3.y+=v3.y; s3.z+=v3.z; s3.w+=v3.w;
    }
    *(float4*)&Bs2[l][o16+0]  = s0;
    *(float4*)&Bs2[l][o16+4]  = s1;
    *(float4*)&Bs2[l][o16+8]  = s2;
    *(float4*)&Bs2[l][o16+12] = s3;
  }
  __syncthreads();
  const int j0 = (tid>>4)*4, u0 = (tid&15)*4;
  float acc[4][4] = {};
  #pragma unroll 8
  for(int l=0;l<64;l++){
    f32x4 a = *(f32x4*)&KT[l][j0];
    f32x4 b = *(f32x4*)&Bs2[l][u0];
    #pragma unroll
    for(int s=0;s<4;s++)
      #pragma unroll
      for(int u=0;u<4;u++) acc[s][u] += a[s]*b[u];
  }
  #pragma unroll
  for(int s=0;s<4;s++)
    #pragma unroll
    for(int u=0;u<4;u++)
      Ct[(u0+u)*72 + j0+s] = f2bf(acc[s][u]);
  __syncthreads();
  {
    int e = tid>>2, j16 = (tid&3)*16;
    u16* op = C2T + ((size_t)n*256 + eb + e)*64 + j16;
    #pragma unroll
    for(int t=0;t<16;t+=4)
      *(ushort4*)(op+t) = *(const ushort4*)&Ct[e*72 + j16 + t];
  }
}

// ---------------- out[i][e] = sum_j Z1[j][i]*C2[j][e] + v[i][e]; MFMA, OM bf16 --------------
__global__ __launch_bounds__(256) void k_out(const float* __restrict__ Z1, const u16* __restrict__ C2T,
                                             const u16* __restrict__ Y, u16* __restrict__ OM){
  __shared__ __align__(16) u16 Cs[256*64];    // [256 e][64 j], gl16-swizzled
  __shared__ __align__(16) u16 Zt[64*72];     // [64 i][72 j]
  const int ib = blockIdx.x*64, n = blockIdx.y;
  const int tid = threadIdx.x, lane = tid&63;
  const int c = tid&15, qq = (tid>>4)&3, wv = tid>>6;
  const int srow  = wv*8 + (lane>>3);
  const int dslot = lane&7;
  const int sgo   = (dslot ^ (lane>>3))*8;
  const int rdswz = (c&7);
  const u16* cb = C2T + (size_t)n*256*64;
  #pragma unroll
  for(int j=0;j<8;j++){
    int r = j*32 + srow;
    gl16(cb + (size_t)r*64 + sgo, &Cs[r*64 + dslot*8]);
  }
  {
    int j = tid>>2, i16 = (tid&3)*16;
    const float* zp = Z1 + ((size_t)n*LND + j)*HWN + ib + i16;
    #pragma unroll
    for(int t=0;t<16;t+=4){
      float4 v = *(const float4*)(zp+t);
      Zt[(i16+t+0)*72 + j] = f2bf(v.x);
      Zt[(i16+t+1)*72 + j] = f2bf(v.y);
      Zt[(i16+t+2)*72 + j] = f2bf(v.z);
      Zt[(i16+t+3)*72 + j] = f2bf(v.w);
    }
  }
  __syncthreads();
  f32x4 acc[4][4];
  #pragma unroll
  for(int mt=0;mt<4;mt++)
    #pragma unroll
    for(int nt=0;nt<4;nt++){ acc[mt][nt][0]=0.f; acc[mt][nt][1]=0.f; acc[mt][nt][2]=0.f; acc[mt][nt][3]=0.f; }
  #pragma unroll
  for(int kt=0;kt<2;kt++){
    const int rslot = ((kt*4+qq)^rdswz)*8;
    short8 af[4], bf_[4];
    #pragma unroll
    for(int mt=0;mt<4;mt++) af[mt] = *(const short8*)&Cs[(wv*64+mt*16+c)*64 + rslot];
    #pragma unroll
    for(int nt=0;nt<4;nt++) bf_[nt] = *(const short8*)&Zt[(nt*16+c)*72 + kt*32 + qq*8];
    #pragma unroll
    for(int mt=0;mt<4;mt++)
      #pragma unroll
      for(int nt=0;nt<4;nt++)
        acc[mt][nt] = __builtin_amdgcn_mfma_f32_16x16x32_bf16(af[mt], bf_[nt], acc[mt][nt], 0, 0, 0);
  }
  const u16* Yb = Y + (size_t)n*M3*HWN;
  u16* ob = OM + (size_t)n*HWN*EDIM;
  #pragma unroll
  for(int mt=0;mt<4;mt++){
    int e = wv*64 + mt*16 + 4*qq;
    #pragma unroll
    for(int nt=0;nt<4;nt++){
      int i = ib + nt*16 + c;
      ushort4 V4 = *(const ushort4*)(Yb + (size_t)i*M3 + 512 + e);
      ushort4 o;
      o.x = f2bf(acc[mt][nt][0] + bf2f(V4.x));
      o.y = f2bf(acc[mt][nt][1] + bf2f(V4.y));
      o.z = f2bf(acc[mt][nt][2] + bf2f(V4.z));
      o.w = f2bf(acc[mt][nt][3] + bf2f(V4.w));
      *(ushort4*)(ob + (size_t)i*EDIM + e) = o;
    }
  }
}

// ---------------- proj GEMM 128x128xK256; B read directly from OM raw [e'][p'] view ---------
__global__ __launch_bounds__(256) void k_proj(const u16* __restrict__ Wb, const u16* __restrict__ OM,
                                              const float* __restrict__ bias, float* __restrict__ out){
  __shared__ __align__(16) u16 As[128*64];
  __shared__ __align__(16) u16 Bt[128*64];    // [128 p][64 e'] slot-XOR layout
  const int bi = blockIdx.x;
  const int n = bi&7, rem = bi>>3;
  const int ch0 = (rem&1)*128, p0 = (rem>>1)*128;
  const int tid = threadIdx.x, lane = tid&63;
  const int c = tid&15, qq = (tid>>4)&3, w4 = tid>>6;
  const int wr0 = (w4&1)*64, wc0 = (w4>>1)*64;
  const u16* omb = OM + (size_t)n*HWN*EDIM;   // flat, viewed [256 e'][4096 p']
  const u16* wb = Wb + (size_t)ch0*EDIM;
  f32x4 acc[4][4];
  #pragma unroll
  for(int mt=0;mt<4;mt++)
    #pragma unroll
    for(int nt=0;nt<4;nt++){ acc[mt][nt][0]=0.f; acc[mt][nt][1]=0.f; acc[mt][nt][2]=0.f; acc[mt][nt][3]=0.f; }
  const int srow  = w4*8 + (lane>>3);
  const int dslot = lane&7;
  const int sgo   = (dslot ^ (lane>>3))*8;
  const int rdswz = (c&7);
  for(int ph=0; ph<4; ph++){
    #pragma unroll
    for(int j=0;j<4;j++){
      int r = j*32 + srow;
      gl16(wb + (size_t)r*EDIM + ph*64 + sgo, &As[r*64 + dslot*8]);
    }
    #pragma unroll
    for(int rep=0; rep<4; rep++){
      int ee = (tid>>4) + 16*rep;                       // 0..63 (e' within phase)
      int pc = (tid&15)*8;                              // 0..120
      uint4 U = *(const uint4*)&omb[(size_t)(ph*64+ee)*HWN + p0 + pc];
      const u16* uv = (const u16*)&U;
      #pragma unroll
      for(int k=0;k<8;k++){
        int p = pc+k;
        int slot = ((ee>>3) ^ (p&7) ^ ((p>>3)&7)) & 7;
        Bt[p*64 + slot*8 + (ee&7)] = uv[k];
      }
    }
    __syncthreads();
    #pragma unroll
    for(int kt=0;kt<2;kt++){
      const int rslot = ((kt*4+qq)^rdswz)*8;
      short8 af[4], bff[4];
      #pragma unroll
      for(int mt=0;mt<4;mt++) af[mt] = *(const short8*)&As[(wr0+mt*16+c)*64 + rslot];
      #pragma unroll
      for(int nt=0;nt<4;nt++){
        int p = wc0 + nt*16 + c;
        int slotB = ((kt*4+qq) ^ (p&7) ^ ((p>>3)&7)) & 7;
        bff[nt] = *(const short8*)&Bt[p*64 + slotB*8];
      }
      #pragma unroll
      for(int mt=0;mt<4;mt++)
        #pragma unroll
        for(int nt=0;nt<4;nt++)
          acc[mt][nt] = __builtin_amdgcn_mfma_f32_16x16x32_bf16(af[mt], bff[nt], acc[mt][nt], 0, 0, 0);
    }
    __syncthreads();
  }
  float* ob = out + (size_t)n*EDIM*HWN;
  #pragma unroll
  for(int mt=0;mt<4;mt++){
    int chb = ch0 + wr0 + mt*16 + 4*qq;
    float b0 = bias[chb], b1 = bias[chb+1], b2 = bias[chb+2], b3 = bias[chb+3];
    #pragma unroll
    for(int nt=0;nt<4;nt++){
      int p = p0 + wc0 + nt*16 + c;
      float* yp = ob + (size_t)chb*HWN + p;
      yp[0]             = acc[mt][nt][0]+b0;
      yp[HWN]           = acc[mt][nt][1]+b1;
      yp[2*(size_t)HWN] = acc[mt][nt][2]+b2;
      yp[3*(size_t)HWN] = acc[mt][nt][3]+b3;
    }
  }
}

extern "C" void kernel_launch(void* const* d_in, const int* in_sizes, int n_in,
                              void* d_out, int out_size, void* d_ws, size_t ws_size,
                              hipStream_t stream){
  (void)out_size; (void)ws_size;
  const float* x     = (const float*)d_in[0];
  const float* w_qkv = (const float*)d_in[1];
  const float* b_qkv = (const float*)d_in[2];
  const float* w_out = (const float*)d_in[3];
  const float* b_out = (const float*)d_in[4];
  for(int i=0;i<n_in;i++){
    switch(in_sizes[i]){
      case 8388608: x     = (const float*)d_in[i]; break;
      case 196608:  w_qkv = (const float*)d_in[i]; break;
      case 768:     b_qkv = (const float*)d_in[i]; break;
      case 65536:   w_out = (const float*)d_in[i]; break;
      case 256:     b_out = (const float*)d_in[i]; break;
      default: break;
    }
  }
  float* out = (float*)d_out;
  char* ws = (char*)d_ws;

  u16*   Y     = (u16*)(ws + 0);              // 50,331,648 B  bf16 [8][768*4096]
  float* qland = (float*)(ws + 50331648);
  float* kland = (float*)(ws + 50855936);
  float* Z1    = (float*)(ws + 51380224);
  float* Z3    = (float*)(ws + 59768832);
  float* KinvT = (float*)(ws + 68157440);
  float* part  = (float*)(ws + 68288512);     // 16 MB region (was Xt -> part)
  u16*   Xt    = (u16*)(ws + 68288512);
  u16*   C2T   = (u16*)(ws + 85065728);       // bf16 [8][256 e][64 j] = 256 KB, ends 85327872
  u16*   NSst  = (u16*)(ws + 85327872);       // bf16 K/V state between NS stages, 131072 B
  u16*   OM    = (u16*)(ws + 86114304);       // 16 MB bf16
  // Wqb overlaps Z3 (Z3 written by k_landgemm AFTER k_qkv consumes Wqb — stream-ordered safe)
  u16*   Wqb   = (u16*)(ws + 59768832);       // 393,216 B bf16 [768][256]
  u16*   Wob   = (u16*)(ws + 102891520);      // 131,072 B bf16 [256][256] (persists to k_proj)

  k_prep    <<<dim3(2056),   256, 0, stream>>>(x, Xt, w_qkv, w_out, Wqb, Wob);
  k_qkv     <<<dim3(1536),   256, 0, stream>>>(Wqb, Xt, b_qkv, Y);
  k_land    <<<dim3(64,8),   256, 0, stream>>>(Y, qland, kland);
  k_landgemm<<<dim3(65,16),  256, 0, stream>>>(Y, qland, kland, Z1, Z3, NSst);
  k_pv      <<<dim3(1032),   256, 0, stream>>>(Z3, Y, part, Z1, NSst, KinvT);
  k_c2      <<<dim3(4,8),    256, 0, stream>>>(KinvT, part, C2T);
  k_out     <<<dim3(64,8),   256, 0, stream>>>(Z1, C2T, Y, OM);
  k_proj    <<<dim3(512),    256, 0, stream>>>(Wob, OM, b_out, out);
}

// Round 13
// 193.388 us; speedup vs baseline: 1.1955x; 1.0101x over previous
//
#include <hip/hip_runtime.h>
#include <hip/hip_bf16.h>

typedef unsigned short u16;
typedef __attribute__((ext_vector_type(4))) float f32x4;
typedef __attribute__((ext_vector_type(8))) short short8;

#define NB   8
#define CIN  256
#define EDIM 256
#define M3   768
#define HWN  4096
#define LND  64
#define NS2  72    // NS LDS row stride (bf16 elems): 144B, 16B aligned

__device__ __forceinline__ float bf2f(u16 u){ return __uint_as_float(((unsigned)u)<<16); }
__device__ __forceinline__ u16 f2bf(float f){ __hip_bfloat16 h = __float2bfloat16(f); return *reinterpret_cast<u16*>(&h); }
__device__ __forceinline__ void bf2x2(unsigned u, float &lo, float &hi){
  lo = __uint_as_float(u<<16);
  hi = __uint_as_float(u & 0xffff0000u);
}

typedef __attribute__((address_space(1))) unsigned as1_uint;
typedef __attribute__((address_space(3))) unsigned as3_uint;
// async global->LDS, 16B per lane; dest must be wave-uniform base + lane*16
__device__ __forceinline__ void gl16(const void* g, void* l){
  __builtin_amdgcn_global_load_lds((const as1_uint*)g, (as3_uint*)l, 16, 0, 0);
}

// ---------------- prep: Xt[n][p][c] (bf16) = transpose of X[n][c][p] (fp32) ----------------
__global__ __launch_bounds__(256) void k_prep(const float* __restrict__ x, u16* __restrict__ Xt,
                                              const float* __restrict__ wq, const float* __restrict__ wo,
                                              u16* __restrict__ Wqb, u16* __restrict__ Wob){
  const int bi = blockIdx.x;
  const int tid = threadIdx.x;
  if(bi >= 2048){
    int ti = (bi-2048)*256 + tid;          // 0..2047
    const float* src; u16* dst;
    if(ti < 1536){ src = wq + (size_t)ti*128;        dst = Wqb + (size_t)ti*128; }
    else         { src = wo + (size_t)(ti-1536)*128; dst = Wob + (size_t)(ti-1536)*128; }
    #pragma unroll
    for(int t=0;t<128;t+=8){
      float4 v0 = *(const float4*)(src+t);
      float4 v1 = *(const float4*)(src+t+4);
      ushort4 o0, o1;
      o0.x=f2bf(v0.x); o0.y=f2bf(v0.y); o0.z=f2bf(v0.z); o0.w=f2bf(v0.w);
      o1.x=f2bf(v1.x); o1.y=f2bf(v1.y); o1.z=f2bf(v1.z); o1.w=f2bf(v1.w);
      *(ushort4*)(dst+t)   = o0;
      *(ushort4*)(dst+t+4) = o1;
    }
    return;
  }
  __shared__ float Ts[64*65];
  const int n = bi>>8, rem = bi&255, ct = rem>>6, pt = rem&63;
  const int c0 = ct*64, p0 = pt*64;
  {
    int cc = tid>>2, pj = (tid&3)*16;
    const float* xp = x + (size_t)n*CIN*HWN + (size_t)(c0+cc)*HWN + p0 + pj;
    #pragma unroll
    for(int j=0;j<16;j++) Ts[cc*65 + pj + j] = xp[j];
  }
  __syncthreads();
  {
    int pp = tid>>2, ej = (tid&3)*16;
    u16* op = Xt + ((size_t)n*HWN + p0 + pp)*CIN + c0 + ej;
    ushort4 o[4];
    #pragma unroll
    for(int j=0;j<16;j++) ((u16*)o)[j] = f2bf(Ts[(ej+j)*65 + pp]);
    *(ushort4*)(op+0)  = o[0];
    *(ushort4*)(op+4)  = o[1];
    *(ushort4*)(op+8)  = o[2];
    *(ushort4*)(op+12) = o[3];
  }
}

// ---------------- QKV GEMM 128x128xK256 bf16 MFMA, global_load_lds + XOR swizzle ------------
__global__ __launch_bounds__(256) void k_qkv(const u16* __restrict__ Wb, const u16* __restrict__ Xt,
                                             const float* __restrict__ bias, u16* __restrict__ Y){
  __shared__ __align__(16) u16 As[128*64];
  __shared__ __align__(16) u16 Bs[128*64];
  const int bi = blockIdx.x;
  const int n = bi&7, rem = bi>>3;
  const int ch0 = (rem%6)*128, p0 = (rem/6)*128;
  const int tid = threadIdx.x, lane = tid&63;
  const int c = tid&15, qq = (tid>>4)&3, w4 = tid>>6;
  const int wr0 = (w4&1)*64, wc0 = (w4>>1)*64;
  const u16* xb = Xt + ((size_t)n*HWN + p0)*CIN;
  const u16* wb = Wb + (size_t)ch0*CIN;
  f32x4 acc[4][4];
  #pragma unroll
  for(int mt=0;mt<4;mt++)
    #pragma unroll
    for(int nt=0;nt<4;nt++){ acc[mt][nt][0]=0.f; acc[mt][nt][1]=0.f; acc[mt][nt][2]=0.f; acc[mt][nt][3]=0.f; }
  const int srow  = w4*8 + (lane>>3);
  const int dslot = lane&7;
  const int sgo   = (dslot ^ (lane>>3))*8;       // swizzled source u16 offset within row-chunk
  const int rdswz = (c&7);                        // read-side row&7
  for(int ph=0; ph<4; ph++){
    #pragma unroll
    for(int j=0;j<4;j++){
      int r = j*32 + srow;
      gl16(wb + (size_t)r*CIN + ph*64 + sgo, &As[r*64 + dslot*8]);
    }
    #pragma unroll
    for(int j=0;j<4;j++){
      int r = j*32 + srow;
      gl16(xb + (size_t)r*CIN + ph*64 + sgo, &Bs[r*64 + dslot*8]);
    }
    __syncthreads();
    #pragma unroll
    for(int kt=0;kt<2;kt++){
      short8 af[4], bff[4];
      const int rslot = ((kt*4+qq)^rdswz)*8;
      #pragma unroll
      for(int mt=0;mt<4;mt++) af[mt]  = *(const short8*)&As[(wr0+mt*16+c)*64 + rslot];
      #pragma unroll
      for(int nt=0;nt<4;nt++) bff[nt] = *(const short8*)&Bs[(wc0+nt*16+c)*64 + rslot];
      #pragma unroll
      for(int mt=0;mt<4;mt++)
        #pragma unroll
        for(int nt=0;nt<4;nt++)
          acc[mt][nt] = __builtin_amdgcn_mfma_f32_16x16x32_bf16(af[mt], bff[nt], acc[mt][nt], 0, 0, 0);
    }
    __syncthreads();
  }
  u16* Yb = Y + (size_t)n*M3*HWN;
  #pragma unroll
  for(int mt=0;mt<4;mt++){
    int chb = ch0 + wr0 + mt*16 + 4*qq;
    float b0 = bias[chb], b1 = bias[chb+1], b2 = bias[chb+2], b3 = bias[chb+3];
    #pragma unroll
    for(int nt=0;nt<4;nt++){
      int p = p0 + wc0 + nt*16 + c;
      u16* yp = Yb + (size_t)chb*HWN + p;
      yp[0]             = f2bf(acc[mt][nt][0]+b0);
      yp[HWN]           = f2bf(acc[mt][nt][1]+b1);
      yp[2*(size_t)HWN] = f2bf(acc[mt][nt][2]+b2);
      yp[3*(size_t)HWN] = f2bf(acc[mt][nt][3]+b3);
    }
  }
}

// ---------------- landmarks ----------------
__global__ void k_land(const u16* __restrict__ Y, float* __restrict__ qland, float* __restrict__ kland){
  const int l = blockIdx.x, n = blockIdx.y, e = threadIdx.x;
  const u16* base = Y + (size_t)n*M3*HWN;
  float qs=0.f, ks=0.f;
  #pragma unroll 8
  for(int m=0;m<64;m++){
    size_t off = (size_t)(l*64+m)*M3;
    qs += bf2f(base[off+e]);
    ks += bf2f(base[off+256+e]);
  }
  qland[((size_t)n*LND+l)*EDIM+e] = qs*(1.f/4096.f);
  kland[((size_t)n*LND+l)*EDIM+e] = ks*(1.f/4096.f);
}

// ---------------- NS 64x64 matmul via bf16 MFMA (per-operand LDS row stride) ----------------
__device__ __forceinline__ void ns_mm2(const u16* L, int sL, const u16* Rt, int sR,
                                       int wv, int q, int c, f32x4 r4[4]){
  short8 a0 = *(const short8*)(L + (size_t)(16*wv + c)*sL + 8*q);
  short8 a1 = *(const short8*)(L + (size_t)(16*wv + c)*sL + 32 + 8*q);
  #pragma unroll
  for(int tc=0;tc<4;tc++){
    f32x4 acc = {0.f,0.f,0.f,0.f};
    short8 b0 = *(const short8*)(Rt + (size_t)(16*tc + c)*sR + 8*q);
    short8 b1 = *(const short8*)(Rt + (size_t)(16*tc + c)*sR + 32 + 8*q);
    acc = __builtin_amdgcn_mfma_f32_16x16x32_bf16(a0, b0, acc, 0, 0, 0);
    acc = __builtin_amdgcn_mfma_f32_16x16x32_bf16(a1, b1, acc, 0, 0, 0);
    r4[tc] = acc;
  }
}

// ---- one rotated NS iteration: 4 barriers (M3 writes KVt — validated rotation) -------------
#define TTS 64
__device__ __forceinline__ void ns_iter(u16* Kb, u16* Vb, u16* Vt, u16* KVb, u16* KVt, u16* Tt,
                                        int wv, int q, int c, bool last, int n,
                                        float* __restrict__ KinvT){
  f32x4 r4[4];
  // M1: KV = K @ V (B^T = Vt) -> KVb (own rows) + KVt (transpose)
  ns_mm2(Kb, NS2, Vt, NS2, wv, q, c, r4);
  #pragma unroll
  for(int tc=0;tc<4;tc++){
    int col = 16*tc + c, row0 = 16*wv + 4*q;
    ushort4 pk;
    pk.x = f2bf(r4[tc][0]); pk.y = f2bf(r4[tc][1]); pk.z = f2bf(r4[tc][2]); pk.w = f2bf(r4[tc][3]);
    KVb[(row0+0)*NS2+col] = pk.x; KVb[(row0+1)*NS2+col] = pk.y;
    KVb[(row0+2)*NS2+col] = pk.z; KVb[(row0+3)*NS2+col] = pk.w;
    *(ushort4*)&KVt[(size_t)col*NS2 + row0] = pk;
  }
  __syncthreads();
  // M2: r = KV @ KV ; Tt = (7KV - r)^T
  ns_mm2(KVb, NS2, KVt, NS2, wv, q, c, r4);
  #pragma unroll
  for(int tc=0;tc<4;tc++){
    int col = 16*tc+c, row0 = 16*wv+4*q;
    ushort4 pk;
    #pragma unroll
    for(int r=0;r<4;r++){
      float kvv = bf2f(KVb[(row0+r)*NS2+col]);
      ((u16*)&pk)[r] = f2bf(7.f*kvv - r4[tc][r]);
    }
    *(ushort4*)&Tt[(size_t)col*TTS + row0] = pk;
  }
  __syncthreads();
  // M3: r = KV @ T ; KVt = (15KV - r)^T   (KVt dead after M2 — no WAR barrier needed)
  ns_mm2(KVb, NS2, Tt, TTS, wv, q, c, r4);
  #pragma unroll
  for(int tc=0;tc<4;tc++){
    int col = 16*tc+c, row0 = 16*wv+4*q;
    ushort4 pk;
    #pragma unroll
    for(int r=0;r<4;r++){
      float kvv = bf2f(KVb[(row0+r)*NS2+col]);
      ((u16*)&pk)[r] = f2bf(15.f*kvv - r4[tc][r]);
    }
    *(ushort4*)&KVt[(size_t)col*NS2 + row0] = pk;
  }
  __syncthreads();
  // M4: r = V @ T2 (B^T = KVt) ; newV = 0.25(13V - r) -> Vb (own rows), Vt (transpose)
  ns_mm2(Vb, NS2, KVt, NS2, wv, q, c, r4);
  #pragma unroll
  for(int tc=0;tc<4;tc++){
    int col = 16*tc+c, row0 = 16*wv+4*q;
    float nv[4]; ushort4 pk;
    #pragma unroll
    for(int r=0;r<4;r++){
      float vv = bf2f(Vb[(row0+r)*NS2+col]);
      nv[r] = 0.25f*(13.f*vv - r4[tc][r]);
      u16 bb = f2bf(nv[r]);
      Vb[(row0+r)*NS2+col] = bb;
      ((u16*)&pk)[r] = bb;
    }
    *(ushort4*)&Vt[(size_t)col*NS2 + row0] = pk;
    if(last){
      *(float4*)&KinvT[(size_t)n*4096 + (size_t)col*64 + row0] = make_float4(nv[0],nv[1],nv[2],nv[3]);
    }
  }
  __syncthreads();
}

// ---------------- NS stage A: k2 (e-chunk 128) + 4-wave softmax + V0 + iters 0-2 ------------
__device__ void ns_body_A(int n, char* smem, const float* __restrict__ qland,
                          const float* __restrict__ kland, u16* __restrict__ NSst){
  u16* Qs = (u16*)(smem + 0);          // [64][136] bf16 (k2 phase only)
  u16* Ks = (u16*)(smem + 17408);      // [64][136]  -> ends 34816
  float* sS = (float*)(smem + 34816);  // [64][66] f32 -> ends 51712
  float* pm = (float*)(smem + 51712);  // 256 f32 scratch
  float* ps = (float*)(smem + 52736);  // 256 f32 scratch -> ends 53760 (<54272)
  u16* Kb  = (u16*)(smem + 0);
  u16* Vb  = (u16*)(smem + 9216);
  u16* Vt  = (u16*)(smem + 18432);
  u16* KVb = (u16*)(smem + 27648);
  u16* KVt = (u16*)(smem + 36864);
  u16* Tt  = (u16*)(smem + 46080);
  const int tid = threadIdx.x;
  const int wv = tid>>6, q = (tid>>4)&3, c = tid&15;
  const float* qb = qland + (size_t)n*LND*EDIM;
  const float* kb = kland + (size_t)n*LND*EDIM;
  f32x4 acc[4];
  #pragma unroll
  for(int t=0;t<4;t++){ acc[t][0]=0.f; acc[t][1]=0.f; acc[t][2]=0.f; acc[t][3]=0.f; }
  for(int e0=0;e0<EDIM;e0+=128){
    __syncthreads();
    {
      int row = tid>>2, c0 = (tid&3)*32;
      const float* qp = qb + (size_t)row*EDIM + e0 + c0;
      const float* kp = kb + (size_t)row*EDIM + e0 + c0;
      u16* qd = &Qs[row*136 + c0];
      u16* kd = &Ks[row*136 + c0];
      #pragma unroll
      for(int j=0;j<32;j+=4){
        float4 qv = *(const float4*)(qp+j);
        float4 kv = *(const float4*)(kp+j);
        ushort4 qo, ko;
        qo.x=f2bf(qv.x); qo.y=f2bf(qv.y); qo.z=f2bf(qv.z); qo.w=f2bf(qv.w);
        ko.x=f2bf(kv.x); ko.y=f2bf(kv.y); ko.z=f2bf(kv.z); ko.w=f2bf(kv.w);
        *(ushort4*)(qd+j) = qo;
        *(ushort4*)(kd+j) = ko;
      }
    }
    __syncthreads();
    #pragma unroll
    for(int kt=0;kt<4;kt++){
      short8 a0 = *(const short8*)&Qs[(16*wv+c)*136 + kt*32 + 8*q];
      #pragma unroll
      for(int tc=0;tc<4;tc++){
        short8 b0 = *(const short8*)&Ks[(16*tc+c)*136 + kt*32 + 8*q];
        acc[tc] = __builtin_amdgcn_mfma_f32_16x16x32_bf16(a0, b0, acc[tc], 0, 0, 0);
      }
    }
  }
  __syncthreads();
  #pragma unroll
  for(int tc=0;tc<4;tc++){
    int col = 16*tc + c, row0 = 16*wv + 4*q;
    sS[(row0+0)*66+col] = acc[tc][0];
    sS[(row0+1)*66+col] = acc[tc][1];
    sS[(row0+2)*66+col] = acc[tc][2];
    sS[(row0+3)*66+col] = acc[tc][3];
  }
  __syncthreads();
  const int jc = tid&63, sl = (tid>>6)*16;
  { // P1: partial column max
    float m = -1e30f;
    for(int i=sl;i<sl+16;i++) m = fmaxf(m, sS[i*66+jc]);
    pm[(tid>>6)*64 + jc] = m;
  }
  __syncthreads();
  { // P2: exp in place + partial column sum
    float m = fmaxf(fmaxf(pm[jc],pm[64+jc]), fmaxf(pm[128+jc],pm[192+jc]));
    float s = 0.f;
    for(int i=sl;i<sl+16;i++){ float e = __expf(sS[i*66+jc]-m); sS[i*66+jc] = e; s += e; }
    ps[(tid>>6)*64 + jc] = s;
  }
  __syncthreads();
  { // P3: normalize -> Kb bf16; partial column |.| sum
    float s = ps[jc]+ps[64+jc]+ps[128+jc]+ps[192+jc];
    float inv = 1.f/s, cs = 0.f;
    for(int i=sl;i<sl+16;i++){
      float kv = sS[i*66+jc]*inv;
      cs += fabsf(kv);
      Kb[i*NS2+jc] = f2bf(kv);
    }
    pm[(tid>>6)*64 + jc] = cs;
  }
  __syncthreads();
  { // P4: partial row |.| sums of Kb
    float rs = 0.f;
    for(int j2=sl;j2<sl+16;j2++) rs += fabsf(bf2f(Kb[jc*NS2+j2]));
    ps[(tid>>6)*64 + jc] = rs;
  }
  __syncthreads();
  if(tid < 64){ // P5: combine + v0/vi via shuffle butterflies
    float cs = pm[tid]+pm[64+tid]+pm[128+tid]+pm[192+tid];
    float rs = ps[tid]+ps[64+tid]+ps[128+tid]+ps[192+tid];
    float v0 = cs, vi = rs;
    #pragma unroll
    for(int o=32;o;o>>=1){ v0 = fmaxf(v0, __shfl_xor(v0,o)); vi = fmaxf(vi, __shfl_xor(vi,o)); }
    if(tid==0) pm[0] = 1.f/(v0*vi);
  }
  __syncthreads();
  { // P6: V0 = K^T * sc
    float sc = pm[0];
    int i = tid>>2, j16 = (tid&3)*16;
    #pragma unroll
    for(int jj=0;jj<16;jj++){
      int j = j16+jj;
      u16 bvv = f2bf(bf2f(Kb[j*NS2+i])*sc);
      Vb[i*NS2+j] = bvv;
      Vt[j*NS2+i] = bvv;
    }
  }
  __syncthreads();
  for(int it=0; it<3; it++)
    ns_iter(Kb, Vb, Vt, KVb, KVt, Tt, wv, q, c, false, n, (float*)0);
  // store K,V (bf16) — after iter-2's end barrier all Vb rows are visible
  {
    int i = tid>>2, j16 = (tid&3)*16;
    u16* kd = NSst + (size_t)n*4096 + i*64 + j16;
    u16* vd = NSst + (size_t)(8+n)*4096 + i*64 + j16;
    #pragma unroll
    for(int t=0;t<16;t+=4){
      *(ushort4*)(kd+t) = *(const ushort4*)&Kb[i*NS2 + j16 + t];
      *(ushort4*)(vd+t) = *(const ushort4*)&Vb[i*NS2 + j16 + t];
    }
  }
}

// ---------------- NS stage B: reload K,V; rebuild Vt; iters 3-5; write KinvT ----------------
__device__ void ns_body_B(int n, char* smem, const u16* __restrict__ NSst, float* __restrict__ KinvT){
  u16* Kb  = (u16*)(smem + 0);
  u16* Vb  = (u16*)(smem + 9216);
  u16* Vt  = (u16*)(smem + 18432);
  u16* KVb = (u16*)(smem + 27648);
  u16* KVt = (u16*)(smem + 36864);
  u16* Tt  = (u16*)(smem + 46080);
  const int tid = threadIdx.x;
  const int wv = tid>>6, q = (tid>>4)&3, c = tid&15;
  {
    int i = tid>>2, j16 = (tid&3)*16;
    const u16* ks = NSst + (size_t)n*4096 + i*64 + j16;
    const u16* vs = NSst + (size_t)(8+n)*4096 + i*64 + j16;
    #pragma unroll
    for(int t=0;t<16;t+=4){
      ushort4 kk = *(const ushort4*)(ks+t);
      ushort4 vv = *(const ushort4*)(vs+t);
      *(ushort4*)&Kb[i*NS2 + j16 + t] = kk;
      *(ushort4*)&Vb[i*NS2 + j16 + t] = vv;
      Vt[(j16+t+0)*NS2 + i] = vv.x;
      Vt[(j16+t+1)*NS2 + i] = vv.y;
      Vt[(j16+t+2)*NS2 + i] = vv.z;
      Vt[(j16+t+3)*NS2 + i] = vv.w;
    }
  }
  __syncthreads();
  for(int it=3; it<6; it++)
    ns_iter(Kb, Vb, Vt, KVb, KVt, Tt, wv, q, c, it==5, n, KinvT);
}

// ---------------- Z1/Z3 landmark GEMM + fused NS stage A (blockIdx.x==64) -------------------
#define LGS 264   // A LDS row stride (u16): 528B, 16B aligned, bank-conflict-free
__global__ __launch_bounds__(256) void k_landgemm(const u16* __restrict__ Y, const float* __restrict__ qland,
                                                  const float* __restrict__ kland, float* __restrict__ Z1,
                                                  float* __restrict__ Z3, u16* __restrict__ NSst){
  __shared__ __align__(16) char usm[54272];
  const int z = blockIdx.y;
  if(blockIdx.x == 64){
    if((z&1)==0) ns_body_A(z>>1, usm, qland, kland, NSst);
    return;
  }
  u16* As = (u16*)usm;                 // [64][LGS]
  u16* BsU = (u16*)(usm + 33792);      // [2][64*64]
  const int n = z>>1, which = z&1;
  const int b0 = blockIdx.x*64;
  const float* land = (which ? qland : kland) + (size_t)n*LND*EDIM;
  const int boff = which ? 256 : 0;
  float* out = (which ? Z3 : Z1) + (size_t)n*LND*HWN;
  const u16* Yb = Y + (size_t)n*M3*HWN + boff;
  const int tid = threadIdx.x, lane = tid&63;
  const int c = tid&15, qq = (tid>>4)&3, wv = tid>>6;
  {
    int r = tid>>2, c0 = (tid&3)*64;
    const float* lp = land + (size_t)r*EDIM + c0;
    u16* dp = &As[r*LGS + c0];
    #pragma unroll
    for(int j=0;j<64;j+=4){
      float4 v = *(const float4*)(lp+j);
      ushort4 o; o.x=f2bf(v.x); o.y=f2bf(v.y); o.z=f2bf(v.z); o.w=f2bf(v.w);
      *(ushort4*)(dp+j) = o;
    }
  }
  const int srow  = wv*8 + (lane>>3);            // 0..31
  const int dslot = lane&7;
  const int sgo   = (dslot ^ (lane>>3))*8;       // row&7 == lane>>3 here
  const int rdswz = (c&7);
  f32x4 acc[4];
  #pragma unroll
  for(int nt=0;nt<4;nt++){ acc[nt][0]=0.f; acc[nt][1]=0.f; acc[nt][2]=0.f; acc[nt][3]=0.f; }
  #pragma unroll
  for(int j=0;j<2;j++){
    int r = j*32 + srow;
    gl16(Yb + (size_t)(b0+r)*M3 + sgo, BsU + r*64 + dslot*8);
  }
  __syncthreads();
  for(int ph=0; ph<4; ph++){
    const int cur = ph&1;
    if(ph<3){
      #pragma unroll
      for(int j=0;j<2;j++){
        int r = j*32 + srow;
        gl16(Yb + (size_t)(b0+r)*M3 + (ph+1)*64 + sgo, BsU + (cur^1)*4096 + r*64 + dslot*8);
      }
    }
    #pragma unroll
    for(int kt=0;kt<2;kt++){
      short8 af = *(const short8*)&As[(16*wv + c)*LGS + ph*64 + kt*32 + qq*8];
      const int rslot = ((kt*4+qq)^rdswz)*8;
      #pragma unroll
      for(int nt=0;nt<4;nt++){
        short8 bff = *(const short8*)&BsU[cur*4096 + (nt*16+c)*64 + rslot];
        acc[nt] = __builtin_amdgcn_mfma_f32_16x16x32_bf16(af, bff, acc[nt], 0, 0, 0);
      }
    }
    __syncthreads();
  }
  const int m0 = 16*wv + 4*qq;
  #pragma unroll
  for(int nt=0;nt<4;nt++){
    int col = b0 + nt*16 + c;
    out[(size_t)(m0+0)*HWN + col] = acc[nt][0];
    out[(size_t)(m0+1)*HWN + col] = acc[nt][1];
    out[(size_t)(m0+2)*HWN + col] = acc[nt][2];
    out[(size_t)(m0+3)*HWN + col] = acc[nt][3];
  }
}

// ---------------- soft1 body: softmax of Z1 over contiguous 4096 ----------------
__device__ void soft1_body(int b, char* smem, float* __restrict__ Z1){
  const int n = b>>6, j = b&63, tid = threadIdx.x;
  float* redm = (float*)smem;
  float* reds = redm + 4;
  float* base = Z1 + ((size_t)n*LND + j)*HWN;
  float v[16];
  float m = -1e30f;
  #pragma unroll
  for(int r=0;r<16;r++){ v[r] = base[r*256 + tid]; m = fmaxf(m, v[r]); }
  #pragma unroll
  for(int o=32;o;o>>=1) m = fmaxf(m, __shfl_xor(m, o));
  const int wid = tid>>6;
  if((tid&63)==0) redm[wid] = m;
  __syncthreads();
  m = fmaxf(fmaxf(redm[0],redm[1]), fmaxf(redm[2],redm[3]));
  float s = 0.f;
  #pragma unroll
  for(int r=0;r<16;r++){ v[r] = __expf(v[r]-m); s += v[r]; }
  #pragma unroll
  for(int o=32;o;o>>=1) s += __shfl_xor(s, o);
  if((tid&63)==0) reds[wid] = s;
  __syncthreads();
  s = reds[0]+reds[1]+reds[2]+reds[3];
  float inv = 1.f/s;
  #pragma unroll
  for(int r=0;r<16;r++) base[r*256 + tid] = v[r]*inv;
}

// ---------------- fused soft3 + PV GEMM + soft1 + NS stage B (blocks 0-7 first) -------------
__global__ __launch_bounds__(256) void k_pv(const float* __restrict__ Z3, const u16* __restrict__ Y,
                                            float* __restrict__ part, float* __restrict__ Z1,
                                            const u16* __restrict__ NSst, float* __restrict__ KinvT){
  __shared__ __align__(16) char smem[54272];
  const int bi = blockIdx.x;
  if(bi < 8){ ns_body_B(bi, smem, NSst, KinvT); return; }
  if(bi >= 520){ soft1_body(bi-520, smem, Z1); return; }
  float* Sf   = (float*)smem;              // [64][132] logits -> exp   (0..33792)
  float* sinv = (float*)(smem + 33792);    // [128] 1/sum               (33792..34304)
  u16*   Asb  = (u16*)(smem + 34304);      // [2][64][64] P bf16, XOR-swizzled (..50688)
  u16*   Vt   = (u16*)smem;                // [128 e][64 j] per phase — overlays Sf (dead)
  const int idx = bi - 8;
  const int kc = idx&31, n = (idx>>5)&7, eh = idx>>8;
  const int jb = kc*128, eb = eh*128;
  const int tid = threadIdx.x, lane = tid&63;
  const int c = tid&15, qq = (tid>>4)&3, wv = tid>>6;
  const u16* Yb = Y + (size_t)n*M3*HWN;       // raw view: V[j][e] = flat[j*768 + 512 + e]
  const float* z3b = Z3 + (size_t)n*LND*HWN;
  // ---- soft3: stage logits ----
  {
    int ibase = (tid>>5)*8, j4 = (tid&31)*4;
    #pragma unroll
    for(int r=0;r<8;r++){
      int i = ibase + r;
      *(float4*)&Sf[i*132 + j4] = *(const float4*)&z3b[(size_t)i*HWN + jb + j4];
    }
  }
  __syncthreads();
  if(tid < 128){
    int j = tid;
    float m = -1e30f;
    for(int i=0;i<64;i++) m = fmaxf(m, Sf[i*132 + j]);
    float s = 0.f;
    for(int i=0;i<64;i++){ float e = __expf(Sf[i*132 + j] - m); Sf[i*132 + j] = e; s += e; }
    sinv[j] = 1.f/s;
  }
  __syncthreads();
  // ---- write P bf16 straight into swizzled A buffers (both phases) ----
  {
    int i = tid>>2, j0q = (tid&3)*32;
    const int iswz = (i&7);
    #pragma unroll
    for(int t=0;t<32;t+=4){
      int jg = j0q + t;                 // 0..127
      int phb = jg>>6, jl = jg&63;
      ushort4 o;
      o.x = f2bf(Sf[i*132 + jg+0]*sinv[jg+0]);
      o.y = f2bf(Sf[i*132 + jg+1]*sinv[jg+1]);
      o.z = f2bf(Sf[i*132 + jg+2]*sinv[jg+2]);
      o.w = f2bf(Sf[i*132 + jg+3]*sinv[jg+3]);
      *(ushort4*)&Asb[phb*4096 + i*64 + ((jl>>3)^iswz)*8 + (jl&7)] = o;
    }
  }
  __syncthreads();   // Sf dead from here; Vt may overlay it
  const int rdswz = (c&7);
  f32x4 acc[4][2];
  #pragma unroll
  for(int mt=0;mt<4;mt++)
    #pragma unroll
    for(int nt=0;nt<2;nt++){ acc[mt][nt][0]=0.f; acc[mt][nt][1]=0.f; acc[mt][nt][2]=0.f; acc[mt][nt][3]=0.f; }
  for(int ph=0; ph<2; ph++){
    #pragma unroll
    for(int rep=0; rep<4; rep++){
      int jl = (tid>>4) + 16*rep;                       // 0..63
      int ec = (tid&15)*8;                              // 0..120
      uint4 U = *(const uint4*)&Yb[(size_t)(jb+ph*64+jl)*M3 + 512 + eb + ec];
      const u16* uv = (const u16*)&U;
      #pragma unroll
      for(int k=0;k<8;k++){
        int e = ec+k;
        int slot = ((jl>>3) ^ (e&7) ^ ((e>>3)&7)) & 7;
        Vt[e*64 + slot*8 + (jl&7)] = uv[k];
      }
    }
    __syncthreads();
    #pragma unroll
    for(int kt=0;kt<2;kt++){
      const int rslotA = ((kt*4+qq)^rdswz)*8;
      short8 af[4];
      #pragma unroll
      for(int mt=0;mt<4;mt++) af[mt] = *(const short8*)&Asb[ph*4096 + (mt*16+c)*64 + rslotA];
      #pragma unroll
      for(int nt=0;nt<2;nt++){
        int e = wv*32 + nt*16 + c;
        int slotB = ((kt*4+qq) ^ (e&7) ^ ((e>>3)&7)) & 7;
        short8 bf_ = *(const short8*)&Vt[e*64 + slotB*8];
        #pragma unroll
        for(int mt=0;mt<4;mt++)
          acc[mt][nt] = __builtin_amdgcn_mfma_f32_16x16x32_bf16(af[mt], bf_, acc[mt][nt], 0, 0, 0);
      }
    }
    __syncthreads();
  }
  float* pb = part + ((size_t)n*32 + kc)*LND*EDIM + eb;
  #pragma unroll
  for(int mt=0;mt<4;mt++){
    int row0 = mt*16 + 4*qq;
    #pragma unroll
    for(int nt=0;nt<2;nt++){
      int e = wv*32 + nt*16 + c;
      pb[(size_t)(row0+0)*EDIM + e] = acc[mt][nt][0];
      pb[(size_t)(row0+1)*EDIM + e] = acc[mt][nt][1];
      pb[(size_t)(row0+2)*EDIM + e] = acc[mt][nt][2];
      pb[(size_t)(row0+3)*EDIM + e] = acc[mt][nt][3];
    }
  }
}

// ---------------- C2T: fused fred+c2, 16-e slices (4x memory parallelism) -------------------
__global__ __launch_bounds__(256) void k_c2(const float* __restrict__ KinvT, const float* __restrict__ part,
                                            u16* __restrict__ C2T){
  const int eb = blockIdx.x*16, n = blockIdx.y, tid = threadIdx.x;
  __shared__ float KT[64][68];
  __shared__ float Bs2[64][20];
  __shared__ u16 Ct[16*72];
  {
    int l = tid>>2, o16 = (tid&3)*16;
    const float* kp = KinvT + (size_t)n*4096 + l*64 + o16;
    #pragma unroll
    for(int t=0;t<16;t+=4) *(float4*)&KT[l][o16+t] = *(const float4*)(kp+t);
    // fused k_fred: B3[l][eb+o4..+4] = sum_kc part[n][kc][l][...]  (kc ascending, bit-identical)
    int o4 = (tid&3)*4;
    const float* pp = part + (size_t)n*32*16384 + (size_t)l*256 + eb + o4;
    float4 s0 = {0,0,0,0};
    for(int kc=0;kc<32;kc++){
      float4 v0 = *(const float4*)(pp + (size_t)kc*16384);
      s0.x+=v0.x; s0.y+=v0.y; s0.z+=v0.z; s0.w+=v0.w;
    }
    *(float4*)&Bs2[l][o4] = s0;
  }
  __syncthreads();
  const int j0 = (tid>>4)*4, u0 = tid&15;
  float acc[4] = {};
  #pragma unroll 8
  for(int l=0;l<64;l++){
    float b = Bs2[l][u0];
    acc[0] += KT[l][j0+0]*b;
    acc[1] += KT[l][j0+1]*b;
    acc[2] += KT[l][j0+2]*b;
    acc[3] += KT[l][j0+3]*b;
  }
  #pragma unroll
  for(int s=0;s<4;s++) Ct[u0*72 + j0+s] = f2bf(acc[s]);
  __syncthreads();
  {
    int e = tid>>4, j16 = (tid&15)*4;
    u16* op = C2T + ((size_t)n*256 + eb + e)*64 + j16;
    *(ushort4*)(op) = *(const ushort4*)&Ct[e*72 + j16];
  }
}

// ---------------- out[i][e] = sum_j Z1[j][i]*C2[j][e] + v[i][e]; MFMA, OM bf16 --------------
__global__ __launch_bounds__(256) void k_out(const float* __restrict__ Z1, const u16* __restrict__ C2T,
                                             const u16* __restrict__ Y, u16* __restrict__ OM){
  __shared__ __align__(16) u16 Cs[256*64];    // [256 e][64 j], gl16-swizzled
  __shared__ __align__(16) u16 Zt[64*72];     // [64 i][72 j]
  const int ib = blockIdx.x*64, n = blockIdx.y;
  const int tid = threadIdx.x, lane = tid&63;
  const int c = tid&15, qq = (tid>>4)&3, wv = tid>>6;
  const int srow  = wv*8 + (lane>>3);
  const int dslot = lane&7;
  const int sgo   = (dslot ^ (lane>>3))*8;
  const int rdswz = (c&7);
  const u16* cb = C2T + (size_t)n*256*64;
  #pragma unroll
  for(int j=0;j<8;j++){
    int r = j*32 + srow;
    gl16(cb + (size_t)r*64 + sgo, &Cs[r*64 + dslot*8]);
  }
  {
    int j = tid>>2, i16 = (tid&3)*16;
    const float* zp = Z1 + ((size_t)n*LND + j)*HWN + ib + i16;
    #pragma unroll
    for(int t=0;t<16;t+=4){
      float4 v = *(const float4*)(zp+t);
      Zt[(i16+t+0)*72 + j] = f2bf(v.x);
      Zt[(i16+t+1)*72 + j] = f2bf(v.y);
      Zt[(i16+t+2)*72 + j] = f2bf(v.z);
      Zt[(i16+t+3)*72 + j] = f2bf(v.w);
    }
  }
  __syncthreads();
  f32x4 acc[4][4];
  #pragma unroll
  for(int mt=0;mt<4;mt++)
    #pragma unroll
    for(int nt=0;nt<4;nt++){ acc[mt][nt][0]=0.f; acc[mt][nt][1]=0.f; acc[mt][nt][2]=0.f; acc[mt][nt][3]=0.f; }
  #pragma unroll
  for(int kt=0;kt<2;kt++){
    const int rslot = ((kt*4+qq)^rdswz)*8;
    short8 af[4], bf_[4];
    #pragma unroll
    for(int mt=0;mt<4;mt++) af[mt] = *(const short8*)&Cs[(wv*64+mt*16+c)*64 + rslot];
    #pragma unroll
    for(int nt=0;nt<4;nt++) bf_[nt] = *(const short8*)&Zt[(nt*16+c)*72 + kt*32 + qq*8];
    #pragma unroll
    for(int mt=0;mt<4;mt++)
      #pragma unroll
      for(int nt=0;nt<4;nt++)
        acc[mt][nt] = __builtin_amdgcn_mfma_f32_16x16x32_bf16(af[mt], bf_[nt], acc[mt][nt], 0, 0, 0);
  }
  const u16* Yb = Y + (size_t)n*M3*HWN;
  u16* ob = OM + (size_t)n*HWN*EDIM;
  #pragma unroll
  for(int mt=0;mt<4;mt++){
    int e = wv*64 + mt*16 + 4*qq;
    #pragma unroll
    for(int nt=0;nt<4;nt++){
      int i = ib + nt*16 + c;
      ushort4 V4 = *(const ushort4*)(Yb + (size_t)i*M3 + 512 + e);
      ushort4 o;
      o.x = f2bf(acc[mt][nt][0] + bf2f(V4.x));
      o.y = f2bf(acc[mt][nt][1] + bf2f(V4.y));
      o.z = f2bf(acc[mt][nt][2] + bf2f(V4.z));
      o.w = f2bf(acc[mt][nt][3] + bf2f(V4.w));
      *(ushort4*)(ob + (size_t)i*EDIM + e) = o;
    }
  }
}

// ---------------- proj GEMM 128x128xK256; B read directly from OM raw [e'][p'] view ---------
__global__ __launch_bounds__(256) void k_proj(const u16* __restrict__ Wb, const u16* __restrict__ OM,
                                              const float* __restrict__ bias, float* __restrict__ out){
  __shared__ __align__(16) u16 As[128*64];
  __shared__ __align__(16) u16 Bt[128*64];    // [128 p][64 e'] slot-XOR layout
  const int bi = blockIdx.x;
  const int n = bi&7, rem = bi>>3;
  const int ch0 = (rem&1)*128, p0 = (rem>>1)*128;
  const int tid = threadIdx.x, lane = tid&63;
  const int c = tid&15, qq = (tid>>4)&3, w4 = tid>>6;
  const int wr0 = (w4&1)*64, wc0 = (w4>>1)*64;
  const u16* omb = OM + (size_t)n*HWN*EDIM;   // flat, viewed [256 e'][4096 p']
  const u16* wb = Wb + (size_t)ch0*EDIM;
  f32x4 acc[4][4];
  #pragma unroll
  for(int mt=0;mt<4;mt++)
    #pragma unroll
    for(int nt=0;nt<4;nt++){ acc[mt][nt][0]=0.f; acc[mt][nt][1]=0.f; acc[mt][nt][2]=0.f; acc[mt][nt][3]=0.f; }
  const int srow  = w4*8 + (lane>>3);
  const int dslot = lane&7;
  const int sgo   = (dslot ^ (lane>>3))*8;
  const int rdswz = (c&7);
  for(int ph=0; ph<4; ph++){
    #pragma unroll
    for(int j=0;j<4;j++){
      int r = j*32 + srow;
      gl16(wb + (size_t)r*EDIM + ph*64 + sgo, &As[r*64 + dslot*8]);
    }
    #pragma unroll
    for(int rep=0; rep<4; rep++){
      int ee = (tid>>4) + 16*rep;                       // 0..63 (e' within phase)
      int pc = (tid&15)*8;                              // 0..120
      uint4 U = *(const uint4*)&omb[(size_t)(ph*64+ee)*HWN + p0 + pc];
      const u16* uv = (const u16*)&U;
      #pragma unroll
      for(int k=0;k<8;k++){
        int p = pc+k;
        int slot = ((ee>>3) ^ (p&7) ^ ((p>>3)&7)) & 7;
        Bt[p*64 + slot*8 + (ee&7)] = uv[k];
      }
    }
    __syncthreads();
    #pragma unroll
    for(int kt=0;kt<2;kt++){
      const int rslot = ((kt*4+qq)^rdswz)*8;
      short8 af[4], bff[4];
      #pragma unroll
      for(int mt=0;mt<4;mt++) af[mt] = *(const short8*)&As[(wr0+mt*16+c)*64 + rslot];
      #pragma unroll
      for(int nt=0;nt<4;nt++){
        int p = wc0 + nt*16 + c;
        int slotB = ((kt*4+qq) ^ (p&7) ^ ((p>>3)&7)) & 7;
        bff[nt] = *(const short8*)&Bt[p*64 + slotB*8];
      }
      #pragma unroll
      for(int mt=0;mt<4;mt++)
        #pragma unroll
        for(int nt=0;nt<4;nt++)
          acc[mt][nt] = __builtin_amdgcn_mfma_f32_16x16x32_bf16(af[mt], bff[nt], acc[mt][nt], 0, 0, 0);
    }
    __syncthreads();
  }
  float* ob = out + (size_t)n*EDIM*HWN;
  #pragma unroll
  for(int mt=0;mt<4;mt++){
    int chb = ch0 + wr0 + mt*16 + 4*qq;
    float b0 = bias[chb], b1 = bias[chb+1], b2 = bias[chb+2], b3 = bias[chb+3];
    #pragma unroll
    for(int nt=0;nt<4;nt++){
      int p = p0 + wc0 + nt*16 + c;
      float* yp = ob + (size_t)chb*HWN + p;
      yp[0]             = acc[mt][nt][0]+b0;
      yp[HWN]           = acc[mt][nt][1]+b1;
      yp[2*(size_t)HWN] = acc[mt][nt][2]+b2;
      yp[3*(size_t)HWN] = acc[mt][nt][3]+b3;
    }
  }
}

extern "C" void kernel_launch(void* const* d_in, const int* in_sizes, int n_in,
                              void* d_out, int out_size, void* d_ws, size_t ws_size,
                              hipStream_t stream){
  (void)out_size; (void)ws_size;
  const float* x     = (const float*)d_in[0];
  const float* w_qkv = (const float*)d_in[1];
  const float* b_qkv = (const float*)d_in[2];
  const float* w_out = (const float*)d_in[3];
  const float* b_out = (const float*)d_in[4];
  for(int i=0;i<n_in;i++){
    switch(in_sizes[i]){
      case 8388608: x     = (const float*)d_in[i]; break;
      case 196608:  w_qkv = (const float*)d_in[i]; break;
      case 768:     b_qkv = (const float*)d_in[i]; break;
      case 65536:   w_out = (const float*)d_in[i]; break;
      case 256:     b_out = (const float*)d_in[i]; break;
      default: break;
    }
  }
  float* out = (float*)d_out;
  char* ws = (char*)d_ws;

  u16*   Y     = (u16*)(ws + 0);              // 50,331,648 B  bf16 [8][768*4096]
  float* qland = (float*)(ws + 50331648);
  float* kland = (float*)(ws + 50855936);
  float* Z1    = (float*)(ws + 51380224);
  float* Z3    = (float*)(ws + 59768832);
  float* KinvT = (float*)(ws + 68157440);
  float* part  = (float*)(ws + 68288512);     // 16 MB region (was Xt -> part)
  u16*   Xt    = (u16*)(ws + 68288512);
  u16*   C2T   = (u16*)(ws + 85065728);       // bf16 [8][256 e][64 j] = 256 KB, ends 85327872
  u16*   NSst  = (u16*)(ws + 85327872);       // bf16 K/V state between NS stages, 131072 B
  u16*   OM    = (u16*)(ws + 86114304);       // 16 MB bf16
  // Wqb overlaps Z3 (Z3 written by k_landgemm AFTER k_qkv consumes Wqb — stream-ordered safe)
  u16*   Wqb   = (u16*)(ws + 59768832);       // 393,216 B bf16 [768][256]
  u16*   Wob   = (u16*)(ws + 102891520);      // 131,072 B bf16 [256][256] (persists to k_proj)

  k_prep    <<<dim3(2056),   256, 0, stream>>>(x, Xt, w_qkv, w_out, Wqb, Wob);
  k_qkv     <<<dim3(1536),   256, 0, stream>>>(Wqb, Xt, b_qkv, Y);
  k_land    <<<dim3(64,8),   256, 0, stream>>>(Y, qland, kland);
  k_landgemm<<<dim3(65,16),  256, 0, stream>>>(Y, qland, kland, Z1, Z3, NSst);
  k_pv      <<<dim3(1032),   256, 0, stream>>>(Z3, Y, part, Z1, NSst, KinvT);
  k_c2      <<<dim3(16,8),   256, 0, stream>>>(KinvT, part, C2T);
  k_out     <<<dim3(64,8),   256, 0, stream>>>(Z1, C2T, Y, OM);
  k_proj    <<<dim3(512),    256, 0, stream>>>(Wob, OM, b_out, out);
}